// Round 15
// baseline (1084.398 us; speedup 1.0000x reference)
//
#include <hip/hip_runtime.h>

// ---------------------------------------------------------------------------
// MultiHeadAttention_50646254354439 — R15: R14 + register-level frag pipeline
// in gemm_320/gemm_out (ds_read[t+1] overlapped under MFMA[t], m201 style).
// Dims: B=1024,S=10,D=1024,E=1024,V=KD=128,H=M=8,K=3,HI=WI=16. N=10240.
// proj=[10240][5120] bf16 = q2|kp|vp fused.
// ---------------------------------------------------------------------------

typedef float    f32x4 __attribute__((ext_vector_type(4)));
typedef short    s16x8 __attribute__((ext_vector_type(8)));
typedef unsigned short u16x8 __attribute__((ext_vector_type(8)));
typedef unsigned short u16;

__device__ __forceinline__ u16 f2bf(float f) {   // RNE float->bf16
  union { float f; unsigned u; } x; x.f = f;
  unsigned r = x.u + 0x7FFFu + ((x.u >> 16) & 1u);
  return (u16)(r >> 16);
}
__device__ __forceinline__ float bf2f(u16 u) {
  union { unsigned u; float f; } x; x.u = ((unsigned)u) << 16;
  return x.f;
}

#define ASYNC16(g, l) __builtin_amdgcn_global_load_lds(                       \
    (const __attribute__((address_space(1))) void*)(g),                       \
    (__attribute__((address_space(3))) void*)(l), 16, 0, 0)
#define WAITV(n) asm volatile("s_waitcnt vmcnt(" #n ")" ::: "memory")
#define WAITL    asm volatile("s_waitcnt lgkmcnt(0)" ::: "memory")
#define SB       __builtin_amdgcn_sched_barrier(0)
#define BAR      __builtin_amdgcn_s_barrier()

// ---------- fp32 -> bf16 elementwise ----------------------------------------
__global__ __launch_bounds__(256) void conv_a(
    const float* __restrict__ src, u16* __restrict__ dst, int n8)
{
  int i = blockIdx.x * 256 + threadIdx.x;
  if (i >= n8) return;
  const float4* s = (const float4*)src + (size_t)i * 2;
  float4 a = s[0], b = s[1];
  u16x8 o;
  o[0] = f2bf(a.x); o[1] = f2bf(a.y); o[2] = f2bf(a.z); o[3] = f2bf(a.w);
  o[4] = f2bf(b.x); o[5] = f2bf(b.y); o[6] = f2bf(b.z); o[7] = f2bf(b.w);
  *(u16x8*)(dst + (size_t)i * 8) = o;
}

// ---------- build fused B^T (K-contiguous) weight matrix, bf16 --------------
__global__ __launch_bounds__(256) void conv_w(
    const float* __restrict__ Wq, const float* __restrict__ Wk,
    const float* __restrict__ Wv, const float* __restrict__ Wo,
    u16* __restrict__ Wcat)
{
  int i = blockIdx.x * 256 + threadIdx.x;   // 6144*128 = 786432 threads
  if (i >= 6144 * 128) return;
  int c = i >> 7;
  int d0 = (i & 127) * 8;
  const float* src; int stride;
  if (c < 1024)      { int kq = c >> 3, h = c & 7;
                       src = Wq + (size_t)h * 131072 + kq;      stride = 128; }
  else if (c < 2048) { int j = c - 1024; int h = j >> 7, k = j & 127;
                       src = Wk + (size_t)h * 131072 + k;       stride = 128; }
  else if (c < 5120) { int j = c - 2048; int h = j / 384, cc = j - h * 384;
                       src = Wv + (size_t)h * 393216 + cc;      stride = 384; }
  else               { int e = c - 5120;
                       src = Wo + e;                            stride = 1024; }
  u16x8 o;
#pragma unroll
  for (int r = 0; r < 8; ++r) o[r] = f2bf(src[(size_t)(d0 + r) * stride]);
  *(u16x8*)(Wcat + (size_t)c * 1024 + d0) = o;
}

// ---------- dw -> bf16 [64][1280] (rows >=60 dummy=row0, never written) -----
__global__ __launch_bounds__(256) void conv_dw(
    const float* __restrict__ dw, u16* __restrict__ dwbf)
{
  int i = blockIdx.x * 256 + threadIdx.x;   // 64*160 = 10240 chunks
  if (i >= 10240) return;
  int row = i / 160, ch = i - row * 160;
  int srow = (row < 60) ? row : 0;
  const float4* s = (const float4*)(dw + (size_t)srow * 1280 + ch * 8);
  float4 a = s[0], b = s[1];
  u16x8 o;
  o[0] = f2bf(a.x); o[1] = f2bf(a.y); o[2] = f2bf(a.z); o[3] = f2bf(a.w);
  o[4] = f2bf(b.x); o[5] = f2bf(b.y); o[6] = f2bf(b.z); o[7] = f2bf(b.w);
  *(u16x8*)(dwbf + (size_t)row * 1280 + ch * 8) = o;
}

// ---------- 320x320 bf16 MFMA GEMM (proj), frag-pipelined -------------------
// 512 blocks = 2 exact rounds; triple-buffered 40KB units; counted vmcnt(5);
// one barrier/tile. NEW (R15): frags[t+1] ds_read'd right after the barrier,
// latency hidden under MFMA[t] which consumes register-resident frags.
// Full unroll -> cur/next register sets SSA-renamed (no copies).
__global__ __launch_bounds__(512, 2) void gemm_320(
    const u16* __restrict__ base, long bOff, u16* __restrict__ C, int ldc)
{
  extern __shared__ __align__(16) char smem[];   // 3 x 40960 = 122880 B
  const int tid = threadIdx.x;
  const int l   = tid & 63;
  const int wid = tid >> 6;
  const int wm  = wid >> 2;
  const int wn  = wid & 3;
  const int row0 = blockIdx.x * 320;
  const int col0 = blockIdx.y * 320;

  int eoff[5];
#pragma unroll
  for (int j = 0; j < 5; ++j) {
    int c = j * 512 + tid;
    int mc = (c < 1280) ? c : c - 1280;
    int rp = mc >> 3, s = mc & 7, gs = s ^ (rp & 7);
    int grow = rp * 2 + (gs >> 2), gk = (gs & 3) * 8;
    eoff[j] = (c < 1280) ? ((row0 + grow) * 1024 + gk)
                         : (int)(bOff + (size_t)(col0 + grow) * 1024 + gk);
  }

#define STG320(tt, bb) do {                                                   \
    _Pragma("unroll")                                                         \
    for (int j_ = 0; j_ < 5; ++j_)                                            \
      ASYNC16(base + eoff[j_] + (tt) * 32,                                    \
              smem + (bb) * 40960 + (j_ * 512 + tid) * 16);                   \
  } while (0)

  const int lrow = l & 15, lk = l >> 4;
  int aoff[10], boff[5];
  {
    int rowA = wm * 160 + lrow;
    int rpA = rowA >> 1, odA = (rowA & 1) << 2;
#pragma unroll
    for (int fm = 0; fm < 10; ++fm) {
      int rp = rpA + fm * 8;
      aoff[fm] = rp * 128 + (((odA | lk) ^ (rp & 7)) * 16);
    }
    int rowB = wn * 80 + lrow;
    int rpB = rowB >> 1, odB = (rowB & 1) << 2;
#pragma unroll
    for (int fn = 0; fn < 5; ++fn) {
      int rp = rpB + fn * 8;
      boff[fn] = 20480 + rp * 128 + (((odB | lk) ^ (rp & 7)) * 16);
    }
  }

  f32x4 acc[10][5];
#pragma unroll
  for (int i = 0; i < 10; ++i)
#pragma unroll
    for (int j = 0; j < 5; ++j) acc[i][j] = (f32x4){0.f, 0.f, 0.f, 0.f};

  // prologue: stage tiles 0,1; own tile-0 loads landed; barrier -> all landed
  STG320(0, 0); STG320(1, 1);
  WAITV(5);
  SB; BAR; SB;
  // read frags[0] (post-barrier: safe)
  s16x8 aC[10], bC[5];
#pragma unroll
  for (int fn = 0; fn < 5; ++fn) bC[fn] = *(const s16x8*)(smem + boff[fn]);
#pragma unroll
  for (int fm = 0; fm < 10; ++fm) aC[fm] = *(const s16x8*)(smem + aoff[fm]);

#pragma unroll
  for (int t = 0; t < 32; ++t) {
    if (t + 2 < 32) STG320(t + 2, (t + 2) % 3);
    if (t + 1 < 32) {
      if (t == 30) { WAITV(0); } else { WAITV(5); }   // own tile-t+1 landed
    }
    SB; BAR; SB;            // all waves' tile-t+1 landed; frags[t] in regs
    s16x8 aN[10], bN[5];
    if (t + 1 < 32) {
      const char* Abn = smem + ((t + 1) % 3) * 40960;
#pragma unroll
      for (int fn = 0; fn < 5; ++fn) bN[fn] = *(const s16x8*)(Abn + boff[fn]);
#pragma unroll
      for (int fm = 0; fm < 10; ++fm) aN[fm] = *(const s16x8*)(Abn + aoff[fm]);
    }
    __builtin_amdgcn_s_setprio(1);
#pragma unroll
    for (int fm = 0; fm < 10; ++fm)
#pragma unroll
      for (int fn = 0; fn < 5; ++fn)
        acc[fm][fn] = __builtin_amdgcn_mfma_f32_16x16x32_bf16(
            aC[fm], bC[fn], acc[fm][fn], 0, 0, 0);
    __builtin_amdgcn_s_setprio(0);
    if (t + 1 < 32) {
#pragma unroll
      for (int fm = 0; fm < 10; ++fm) aC[fm] = aN[fm];
#pragma unroll
      for (int fn = 0; fn < 5; ++fn) bC[fn] = bN[fn];
    }
  }
#undef STG320

  const int crow = l >> 4, ccol = l & 15;
#pragma unroll
  for (int fm = 0; fm < 10; ++fm)
#pragma unroll
    for (int fn = 0; fn < 5; ++fn) {
      size_t rb = (size_t)(row0 + wm * 160 + fm * 16 + crow * 4);
      int col = col0 + wn * 80 + fn * 16 + ccol;
#pragma unroll
      for (int r = 0; r < 4; ++r)
        C[(rb + r) * ldc + col] = f2bf(acc[fm][fn][r]);
    }
}

// ---------- out GEMM: 160x256 tile, 256 blocks = 1 round, frag-pipelined ----
__global__ __launch_bounds__(512, 2) void gemm_out(
    const u16* __restrict__ A, const u16* __restrict__ Bt,
    float* __restrict__ C, int ldc)
{
  extern __shared__ __align__(16) char smem[];   // 3 x 26624 = 79872 B
  const int tid = threadIdx.x;
  const int l   = tid & 63;
  const int wid = tid >> 6;
  const int wm  = wid >> 2;
  const int wn  = wid & 3;
  const int row0 = blockIdx.x * 160;
  const int col0 = blockIdx.y * 256;

  const u16* gsrc[4];
  bool gact[4];
#pragma unroll
  for (int j = 0; j < 4; ++j) {
    int c = j * 512 + tid;
    gact[j] = (c < 1664);
    int cc = gact[j] ? c : 0;
    int mc = (cc < 640) ? cc : cc - 640;
    int rp = mc >> 3, s = mc & 7, gs = s ^ (rp & 7);
    int grow = rp * 2 + (gs >> 2), gk = (gs & 3) * 8;
    gsrc[j] = (cc < 640) ? (A + (size_t)(row0 + grow) * 1024 + gk)
                         : (Bt + (size_t)(col0 + grow) * 1024 + gk);
  }

#define STGO(tt, bb) do {                                                     \
    _Pragma("unroll")                                                         \
    for (int j_ = 0; j_ < 4; ++j_)                                            \
      if (gact[j_])                                                           \
        ASYNC16(gsrc[j_] + (tt) * 32,                                         \
                smem + (bb) * 26624 + (j_ * 512 + tid) * 16);                 \
  } while (0)

  const int lrow = l & 15, lk = l >> 4;
  int aoff[5], boff[4];
  {
    int rowA = wm * 80 + lrow;
    int rpA = rowA >> 1, odA = (rowA & 1) << 2;
#pragma unroll
    for (int fm = 0; fm < 5; ++fm) {
      int rp = rpA + fm * 8;
      aoff[fm] = rp * 128 + (((odA | lk) ^ (rp & 7)) * 16);
    }
    int rowB = wn * 64 + lrow;
    int rpB = rowB >> 1, odB = (rowB & 1) << 2;
#pragma unroll
    for (int fn = 0; fn < 4; ++fn) {
      int rp = rpB + fn * 8;
      boff[fn] = 10240 + rp * 128 + (((odB | lk) ^ (rp & 7)) * 16);
    }
  }

  f32x4 acc[5][4];
#pragma unroll
  for (int i = 0; i < 5; ++i)
#pragma unroll
    for (int j = 0; j < 4; ++j) acc[i][j] = (f32x4){0.f, 0.f, 0.f, 0.f};

  STGO(0, 0); STGO(1, 1);
  WAITV(3);
  SB; BAR; SB;
  s16x8 aC[5], bC[4];
#pragma unroll
  for (int fn = 0; fn < 4; ++fn) bC[fn] = *(const s16x8*)(smem + boff[fn]);
#pragma unroll
  for (int fm = 0; fm < 5; ++fm) aC[fm] = *(const s16x8*)(smem + aoff[fm]);

#pragma unroll
  for (int t = 0; t < 32; ++t) {
    if (t + 2 < 32) STGO(t + 2, (t + 2) % 3);
    if (t + 1 < 32) {
      if (t == 30) { WAITV(0); } else { WAITV(3); }
    }
    SB; BAR; SB;
    s16x8 aN[5], bN[4];
    if (t + 1 < 32) {
      const char* Abn = smem + ((t + 1) % 3) * 26624;
#pragma unroll
      for (int fn = 0; fn < 4; ++fn) bN[fn] = *(const s16x8*)(Abn + boff[fn]);
#pragma unroll
      for (int fm = 0; fm < 5; ++fm) aN[fm] = *(const s16x8*)(Abn + aoff[fm]);
    }
    __builtin_amdgcn_s_setprio(1);
#pragma unroll
    for (int fm = 0; fm < 5; ++fm)
#pragma unroll
      for (int fn = 0; fn < 4; ++fn)
        acc[fm][fn] = __builtin_amdgcn_mfma_f32_16x16x32_bf16(
            aC[fm], bC[fn], acc[fm][fn], 0, 0, 0);
    __builtin_amdgcn_s_setprio(0);
    if (t + 1 < 32) {
#pragma unroll
      for (int fm = 0; fm < 5; ++fm) aC[fm] = aN[fm];
#pragma unroll
      for (int fn = 0; fn < 4; ++fn) bC[fn] = bN[fn];
    }
  }
#undef STGO

  const int crow = l >> 4, ccol = l & 15;
#pragma unroll
  for (int fm = 0; fm < 5; ++fm)
#pragma unroll
    for (int fn = 0; fn < 4; ++fn) {
      size_t rb = (size_t)(row0 + wm * 80 + fm * 16 + crow * 4);
      int col = col0 + wn * 64 + fn * 16 + ccol;
#pragma unroll
      for (int r = 0; r < 4; ++r)
        C[(rb + r) * ldc + col] = acc[fm][fn][r];
    }
}

// ---------- deltas = q2view[8192][1280] @ dwbf^T + db, pipelined MFMA -------
__global__ __launch_bounds__(256) void delta_mfma(
    const u16* __restrict__ proj, const u16* __restrict__ dwbf,
    const float* __restrict__ db, float* __restrict__ deltas)
{
  __shared__ __align__(16) u16 As[4][64 * 32];
  __shared__ __align__(16) u16 Bs[4][64 * 32];
  const int tid  = threadIdx.x;
  const int lane = tid & 63;
  const int w    = tid >> 6;
  const int row0 = blockIdx.x * 64;
  const int wr   = w * 16;
  const int lrow = lane & 15;
  const int lk   = lane >> 4;

  f32x4 acc[4];
#pragma unroll
  for (int j = 0; j < 4; ++j) acc[j] = (f32x4){0.f, 0.f, 0.f, 0.f};

  const size_t lin0 = (size_t)(row0 + (tid >> 2)) * 1280 + (tid & 3) * 8;
  const u16* Bg = dwbf + (size_t)(tid >> 2) * 1280 + (tid & 3) * 8;

#define STD(kk, bb) do {                                                      \
    size_t lin_ = lin0 + (kk) * 32;                                           \
    ASYNC16(proj + (lin_ >> 10) * 5120 + (lin_ & 1023),                       \
            (char*)As + (bb) * 4096 + w * 1024);                              \
    ASYNC16(Bg + (kk) * 32, (char*)Bs + (bb) * 4096 + w * 1024);              \
  } while (0)

  const int aoff = (wr + lrow) * 64 + lk * 16;
  int boff[4];
#pragma unroll
  for (int f = 0; f < 4; ++f) boff[f] = (f * 16 + lrow) * 64 + lk * 16;

  STD(0, 0); STD(1, 1); STD(2, 2);
  WAITV(4);
  SB; BAR; SB;

  for (int k = 0; k < 40; ++k) {
    const int bb = k & 3;
    if (k + 3 < 40) STD(k + 3, (k + 3) & 3);
    s16x8 af = *(const s16x8*)((const char*)As + bb * 4096 + aoff);
#pragma unroll
    for (int fn = 0; fn < 4; ++fn) {
      s16x8 bfr = *(const s16x8*)((const char*)Bs + bb * 4096 + boff[fn]);
      acc[fn] = __builtin_amdgcn_mfma_f32_16x16x32_bf16(af, bfr, acc[fn], 0, 0, 0);
    }
    if (k < 37)      { WAITV(4); }
    else if (k == 37){ WAITV(2); }
    else if (k == 38){ WAITV(0); }
    SB; BAR; SB;
  }
#undef STD

  const int crow = lane >> 4;
  const int ccol = lane & 15;
#pragma unroll
  for (int fn = 0; fn < 4; ++fn) {
    int col = fn * 16 + ccol;
    if (col < 60) {
      float d = db[col];
      size_t rb = (size_t)(row0 + wr + crow * 4);
#pragma unroll
      for (int r = 0; r < 4; ++r)
        deltas[(rb + r) * 60 + col] = acc[fn][r] + d;
    }
  }
}

// ---------- coords: pd = ref + deltas ; L2-normalize over the hi axis -------
__global__ void coords_kernel(const float* __restrict__ deltas,
                              float* __restrict__ vgx, float* __restrict__ vgy)
{
  int g = blockIdx.x * 256 + threadIdx.x;
  if (g >= 32 * 16 * 10 * 3) return;
  int kk = g % 3, tmp = g / 3;
  int s = tmp % 10; tmp /= 10;
  int wi = tmp % 16; int bnm = tmp / 16;
  float gxr = wi * (1.0f / 15.0f);
  float px[16], py[16];
  float sx = 0.f, sy = 0.f;
#pragma unroll
  for (int hi = 0; hi < 16; ++hi) {
    size_t base = ((size_t)((bnm * 16 + hi) * 16 + wi)) * 60 + (s * 3 + kk) * 2;
    float x = gxr + deltas[base];
    float y = hi * (1.0f / 15.0f) + deltas[base + 1];
    px[hi] = x; py[hi] = y;
    sx += x * x; sy += y * y;
  }
  float rx = 1.0f / fmaxf(sqrtf(sx), 1e-12f);
  float ry = 1.0f / fmaxf(sqrtf(sy), 1e-12f);
#pragma unroll
  for (int hi = 0; hi < 16; ++hi) {
    size_t o = ((size_t)((bnm * 16 + hi) * 16 + wi) * 10 + s) * 3 + kk;
    vgx[o] = px[hi] * rx;
    vgy[o] = py[hi] * ry;
  }
}

// ---------- MFMA attention (R9 version, measured-best) ----------------------
__global__ __launch_bounds__(256) void attn_mfma(
    const u16* __restrict__ proj, const float* __restrict__ vgx,
    const float* __restrict__ vgy, u16* __restrict__ headf,
    float* __restrict__ attn0)
{
  const int bid = blockIdx.x;
  const int m = bid >> 10, b = bid & 1023;
  const int tid = threadIdx.x;
  const int lane = tid & 63;
  const int w = tid >> 6;

  __shared__ __align__(16) u16 ksb[32][136];
  __shared__ __align__(16) u16 vt[128][32];
  __shared__ __align__(16) u16 pl[16][40];
  __shared__ float wst[30][4];
  __shared__ int   cst[30][4];

  s16x8 aq[4];
  if (w == 0) {
    size_t linb = (size_t)bid * 1280 + (size_t)(lane & 15) * 128 + (lane >> 4) * 8;
#pragma unroll
    for (int kk = 0; kk < 4; ++kk) {
      size_t lin = linb + kk * 32;
      aq[kk] = *(const s16x8*)(proj + (lin >> 10) * 5120 + (lin & 1023));
    }
  }

  if (tid < 30) {
    int t = tid, kk = t / 10, sk = t % 10;
    size_t ci = ((size_t)bid * 10 + sk) * 3 + kk;
    float gx = vgx[ci], gy = vgy[ci];
    float ix = (gx + 1.0f) * 8.0f - 0.5f;
    float iy = (gy + 1.0f) * 8.0f - 0.5f;
    float x0f = floorf(ix), y0f = floorf(iy);
    float wx1 = ix - x0f, wx0 = 1.0f - wx1;
    float wy1 = iy - y0f, wy0 = 1.0f - wy1;
    float x1f = x0f + 1.0f, y1f = y0f + 1.0f;
    bool vx0 = (x0f >= 0.f) && (x0f <= 15.f);
    bool vx1 = (x1f >= 0.f) && (x1f <= 15.f);
    bool vy0 = (y0f >= 0.f) && (y0f <= 15.f);
    bool vy1 = (y1f >= 0.f) && (y1f <= 15.f);
    int x0 = min(max((int)x0f, 0), 15);
    int x1 = min(max((int)x1f, 0), 15);
    int y0 = min(max((int)y0f, 0), 15);
    int y1 = min(max((int)y1f, 0), 15);
    wst[t][0] = wx0 * wy0 * ((vx0 && vy0) ? 1.f : 0.f);
    wst[t][1] = wx1 * wy0 * ((vx1 && vy0) ? 1.f : 0.f);
    wst[t][2] = wx0 * wy1 * ((vx0 && vy1) ? 1.f : 0.f);
    wst[t][3] = wx1 * wy1 * ((vx1 && vy1) ? 1.f : 0.f);
    cst[t][0] = x0; cst[t][1] = x1; cst[t][2] = y0; cst[t][3] = y1;
  }
  __syncthreads();

  for (int i = tid; i < 512; i += 256) {
    int t = i & 31, c = i >> 5;
    u16x8 v = (u16x8){0, 0, 0, 0, 0, 0, 0, 0};
    if (t < 30) {
      int sv = t / 3, cv = t - sv * 3;
      v = *(const u16x8*)(proj + ((size_t)(b * 10 + sv)) * 5120 + 2048 +
                          m * 384 + cv * 128 + c * 8);
    }
#pragma unroll
    for (int r = 0; r < 8; ++r)
      vt[8 * c + r][t ^ (8 * (r & 3))] = v[r];
  }

  {
    int pb = (b >> 8) << 8;
    for (int i = tid; i < 480; i += 256) {
      int t = i >> 4, c = i & 15;
      int sk = t % 10;
      int x0 = cst[t][0], x1 = cst[t][1], y0 = cst[t][2], y1 = cst[t][3];
      float w00 = wst[t][0], w10 = wst[t][1], w01 = wst[t][2], w11 = wst[t][3];
      size_t colo = 1024 + (size_t)m * 128 + c * 8;
      const u16x8 f00 = *(const u16x8*)&proj[((size_t)((pb + y0 * 16 + x0) * 10 + sk)) * 5120 + colo];
      const u16x8 f10 = *(const u16x8*)&proj[((size_t)((pb + y0 * 16 + x1) * 10 + sk)) * 5120 + colo];
      const u16x8 f01 = *(const u16x8*)&proj[((size_t)((pb + y1 * 16 + x0) * 10 + sk)) * 5120 + colo];
      const u16x8 f11 = *(const u16x8*)&proj[((size_t)((pb + y1 * 16 + x1) * 10 + sk)) * 5120 + colo];
      u16x8 o;
#pragma unroll
      for (int r = 0; r < 8; ++r) {
        float acc = w00 * bf2f(f00[r]) + w10 * bf2f(f10[r]) +
                    w01 * bf2f(f01[r]) + w11 * bf2f(f11[r]);
        o[r] = f2bf(acc);
      }
      *(u16x8*)&ksb[t][c * 8] = o;
    }
  }
  __syncthreads();

  if (w == 0) {
    f32x4 dq[2];
    dq[0] = (f32x4){0.f, 0.f, 0.f, 0.f};
    dq[1] = (f32x4){0.f, 0.f, 0.f, 0.f};
    const int lr = lane & 15, g = lane >> 4;
#pragma unroll
    for (int kk = 0; kk < 4; ++kk) {
      s16x8 b0 = *(const s16x8*)&ksb[lr][g * 8 + kk * 32];
      s16x8 b1 = *(const s16x8*)&ksb[16 + lr][g * 8 + kk * 32];
      dq[0] = __builtin_amdgcn_mfma_f32_16x16x32_bf16(aq[kk], b0, dq[0], 0, 0, 0);
      dq[1] = __builtin_amdgcn_mfma_f32_16x16x32_bf16(aq[kk], b1, dq[1], 0, 0, 0);
    }
    float p[2][4];
#pragma unroll
    for (int f = 0; f < 2; ++f) {
      int t = lr + 16 * f;
#pragma unroll
      for (int r = 0; r < 4; ++r) {
        float v = dq[f][r] * 0.08838834764831845f;
        p[f][r] = (t < 30) ? v : -1e30f;
      }
    }
#pragma unroll
    for (int r = 0; r < 4; ++r) {
      float mx = fmaxf(p[0][r], p[1][r]);
#pragma unroll
      for (int msk = 1; msk <= 8; msk <<= 1) mx = fmaxf(mx, __shfl_xor(mx, msk));
      float e0 = __expf(p[0][r] - mx);
      float e1 = __expf(p[1][r] - mx);
      float sm = e0 + e1;
#pragma unroll
      for (int msk = 1; msk <= 8; msk <<= 1) sm += __shfl_xor(sm, msk);
      float inv = 1.0f / sm;
      p[0][r] = e0 * inv;
      p[1][r] = e1 * inv;
    }
    if (g == 0) {
      attn0[(size_t)bid * 30 + lr] = p[0][0];
      if (lr < 14) attn0[(size_t)bid * 30 + 16 + lr] = p[1][0];
    }
#pragma unroll
    for (int f = 0; f < 2; ++f)
#pragma unroll
      for (int r = 0; r < 4; ++r)
        pl[g * 4 + r][lr + 16 * f] = f2bf(p[f][r]);
  }
  __syncthreads();

  const int lr = lane & 15, g = lane >> 4;
  s16x8 pa = *(const s16x8*)&pl[lr][g * 8];
#pragma unroll
  for (int qf = 0; qf < 2; ++qf) {
    int fv = w * 2 + qf;
    int v = fv * 16 + lr;
    s16x8 bv = *(const s16x8*)&vt[v][8 * (g ^ (v & 3))];
    f32x4 acc = (f32x4){0.f, 0.f, 0.f, 0.f};
    acc = __builtin_amdgcn_mfma_f32_16x16x32_bf16(pa, bv, acc, 0, 0, 0);
#pragma unroll
    for (int r = 0; r < 4; ++r) {
      int s = g * 4 + r;
      if (s < 10)
        headf[((size_t)(b * 10 + s)) * 1024 + m * 128 + v] = f2bf(acc[r]);
    }
  }
}

// ---------- attn_map[b][t] = mean_m attn0[m][b][t] --------------------------
__global__ void attnmap_kernel(const float* __restrict__ attn0, float* __restrict__ outa)
{
  int i = blockIdx.x * 256 + threadIdx.x;
  if (i >= 30720) return;
  int b = i / 30, t = i % 30;
  float s = 0.f;
  for (int mm = 0; mm < 8; ++mm) s += attn0[((size_t)mm * 1024 + b) * 30 + t];
  outa[i] = 0.125f * s;
}

// ---------------------------------------------------------------------------
extern "C" void kernel_launch(void* const* d_in, const int* in_sizes, int n_in,
                              void* d_out, int out_size, void* d_ws, size_t ws_size,
                              hipStream_t stream)
{
  const float* q  = (const float*)d_in[0];
  const float* Wq = (const float*)d_in[1];
  const float* Wk = (const float*)d_in[2];
  const float* Wv = (const float*)d_in[3];
  const float* Wo = (const float*)d_in[4];
  const float* dw = (const float*)d_in[5];
  const float* db = (const float*)d_in[6];
  float* out = (float*)d_out;
  float* attn_out = out + 10485760;

  // workspace layout (bytes): total ~165 MB. Wcat MUST follow Abf.
  char* p = (char*)d_ws;
  u16*   Abf   = (u16*)p;   p += 20971520;    // [10240][1024] bf16
  u16*   Wcat  = (u16*)p;   p += 12582912;    // [6144][1024] bf16 (B^T fused)
  u16*   proj  = (u16*)p;   p += 104857600;   // [10240][5120] bf16 (q2|kp|vp)
  u16*   headf = (u16*)p;   p += 20971520;    // [10240][1024] bf16
  u16*   dwbf  = (u16*)p;   p += 163840;      // [64][1280] bf16
  float* dels  = (float*)p; p += 1966080;     // [8192][60]
  float* vgxp  = (float*)p; p += 983040;
  float* vgyp  = (float*)p; p += 983040;
  float* attn0 = (float*)p; p += 983040;

  conv_a<<<dim3(5120), dim3(256), 0, stream>>>(q, Abf, 1310720);
  conv_w<<<dim3(3072), dim3(256), 0, stream>>>(Wq, Wk, Wv, Wo, Wcat);
  conv_dw<<<dim3(40), dim3(256), 0, stream>>>(dw, dwbf);

  // fused projections: proj = Abf @ Wcat[0:5120]^T; 512 blocks = 2 rounds
  gemm_320<<<dim3(32, 16), dim3(512), 122880, stream>>>(
      Abf, 10485760L, proj, 5120);

  delta_mfma<<<dim3(128), dim3(256), 0, stream>>>(proj, dwbf, db, dels);
  coords_kernel<<<dim3(60), dim3(256), 0, stream>>>(dels, vgxp, vgyp);
  attn_mfma<<<dim3(8192), dim3(256), 0, stream>>>(proj, vgxp, vgyp, headf, attn0);
  attnmap_kernel<<<dim3(120), dim3(256), 0, stream>>>(attn0, attn_out);

  // out = headf @ Wo^T (Wcat rows 5120..6143); 64x4 = 256 blocks = 1 round
  gemm_out<<<dim3(64, 4), dim3(512), 79872, stream>>>(
      headf, Wcat + (size_t)5120 * 1024, out, 1024);
}

// Round 16
// 234.312 us; speedup vs baseline: 4.6280x; 4.6280x over previous
//
#include <hip/hip_runtime.h>

// ---------------------------------------------------------------------------
// MultiHeadAttention_50646254354439 — R16: exact R14 (best, 235.6us) +
// delta_mfma split to 256 blocks (full chip). R11/R15 lesson: gemm_320's
// register file is saturated (200 AGPR acc + ~60 VGPR); any added per-wave
// register state (dbuf frags, extra occupancy) spills catastrophically.
// Dims: B=1024,S=10,D=1024,E=1024,V=KD=128,H=M=8,K=3,HI=WI=16. N=10240.
// proj=[10240][5120] bf16 = q2|kp|vp fused.
// ---------------------------------------------------------------------------

typedef float    f32x4 __attribute__((ext_vector_type(4)));
typedef short    s16x8 __attribute__((ext_vector_type(8)));
typedef unsigned short u16x8 __attribute__((ext_vector_type(8)));
typedef unsigned short u16;

__device__ __forceinline__ u16 f2bf(float f) {   // RNE float->bf16
  union { float f; unsigned u; } x; x.f = f;
  unsigned r = x.u + 0x7FFFu + ((x.u >> 16) & 1u);
  return (u16)(r >> 16);
}
__device__ __forceinline__ float bf2f(u16 u) {
  union { unsigned u; float f; } x; x.u = ((unsigned)u) << 16;
  return x.f;
}

#define ASYNC16(g, l) __builtin_amdgcn_global_load_lds(                       \
    (const __attribute__((address_space(1))) void*)(g),                       \
    (__attribute__((address_space(3))) void*)(l), 16, 0, 0)
#define WAITV(n) asm volatile("s_waitcnt vmcnt(" #n ")" ::: "memory")
#define WAITL    asm volatile("s_waitcnt lgkmcnt(0)" ::: "memory")
#define SB       __builtin_amdgcn_sched_barrier(0)
#define BAR      __builtin_amdgcn_s_barrier()

// ---------- fp32 -> bf16 elementwise ----------------------------------------
__global__ __launch_bounds__(256) void conv_a(
    const float* __restrict__ src, u16* __restrict__ dst, int n8)
{
  int i = blockIdx.x * 256 + threadIdx.x;
  if (i >= n8) return;
  const float4* s = (const float4*)src + (size_t)i * 2;
  float4 a = s[0], b = s[1];
  u16x8 o;
  o[0] = f2bf(a.x); o[1] = f2bf(a.y); o[2] = f2bf(a.z); o[3] = f2bf(a.w);
  o[4] = f2bf(b.x); o[5] = f2bf(b.y); o[6] = f2bf(b.z); o[7] = f2bf(b.w);
  *(u16x8*)(dst + (size_t)i * 8) = o;
}

// ---------- build fused B^T (K-contiguous) weight matrix, bf16 --------------
__global__ __launch_bounds__(256) void conv_w(
    const float* __restrict__ Wq, const float* __restrict__ Wk,
    const float* __restrict__ Wv, const float* __restrict__ Wo,
    u16* __restrict__ Wcat)
{
  int i = blockIdx.x * 256 + threadIdx.x;   // 6144*128 = 786432 threads
  if (i >= 6144 * 128) return;
  int c = i >> 7;
  int d0 = (i & 127) * 8;
  const float* src; int stride;
  if (c < 1024)      { int kq = c >> 3, h = c & 7;
                       src = Wq + (size_t)h * 131072 + kq;      stride = 128; }
  else if (c < 2048) { int j = c - 1024; int h = j >> 7, k = j & 127;
                       src = Wk + (size_t)h * 131072 + k;       stride = 128; }
  else if (c < 5120) { int j = c - 2048; int h = j / 384, cc = j - h * 384;
                       src = Wv + (size_t)h * 393216 + cc;      stride = 384; }
  else               { int e = c - 5120;
                       src = Wo + e;                            stride = 1024; }
  u16x8 o;
#pragma unroll
  for (int r = 0; r < 8; ++r) o[r] = f2bf(src[(size_t)(d0 + r) * stride]);
  *(u16x8*)(Wcat + (size_t)c * 1024 + d0) = o;
}

// ---------- dw -> bf16 [64][1280] (rows >=60 dummy=row0, never written) -----
__global__ __launch_bounds__(256) void conv_dw(
    const float* __restrict__ dw, u16* __restrict__ dwbf)
{
  int i = blockIdx.x * 256 + threadIdx.x;   // 64*160 = 10240 chunks
  if (i >= 10240) return;
  int row = i / 160, ch = i - row * 160;
  int srow = (row < 60) ? row : 0;
  const float4* s = (const float4*)(dw + (size_t)srow * 1280 + ch * 8);
  float4 a = s[0], b = s[1];
  u16x8 o;
  o[0] = f2bf(a.x); o[1] = f2bf(a.y); o[2] = f2bf(a.z); o[3] = f2bf(a.w);
  o[4] = f2bf(b.x); o[5] = f2bf(b.y); o[6] = f2bf(b.z); o[7] = f2bf(b.w);
  *(u16x8*)(dwbf + (size_t)row * 1280 + ch * 8) = o;
}

// ---------- 320x320 bf16 MFMA GEMM (proj): C = A @ Bt^T ---------------------
// R9/R14-proven: 512 blocks = 2 exact rounds, triple-buffered 40KB units,
// counted vmcnt(5), one barrier/tile. DO NOT add register state (R11/R15).
__global__ __launch_bounds__(512, 2) void gemm_320(
    const u16* __restrict__ base, long bOff, u16* __restrict__ C, int ldc)
{
  extern __shared__ __align__(16) char smem[];   // 3 x 40960 = 122880 B
  const int tid = threadIdx.x;
  const int l   = tid & 63;
  const int wid = tid >> 6;
  const int wm  = wid >> 2;
  const int wn  = wid & 3;
  const int row0 = blockIdx.x * 320;
  const int col0 = blockIdx.y * 320;

  int eoff[5];
#pragma unroll
  for (int j = 0; j < 5; ++j) {
    int c = j * 512 + tid;
    int mc = (c < 1280) ? c : c - 1280;
    int rp = mc >> 3, s = mc & 7, gs = s ^ (rp & 7);
    int grow = rp * 2 + (gs >> 2), gk = (gs & 3) * 8;
    eoff[j] = (c < 1280) ? ((row0 + grow) * 1024 + gk)
                         : (int)(bOff + (size_t)(col0 + grow) * 1024 + gk);
  }

#define STG320(tt, bb) do {                                                   \
    _Pragma("unroll")                                                         \
    for (int j_ = 0; j_ < 5; ++j_)                                            \
      ASYNC16(base + eoff[j_] + (tt) * 32,                                    \
              smem + (bb) * 40960 + (j_ * 512 + tid) * 16);                   \
  } while (0)

  const int lrow = l & 15, lk = l >> 4;
  int aoff[10], boff[5];
  {
    int rowA = wm * 160 + lrow;
    int rpA = rowA >> 1, odA = (rowA & 1) << 2;
#pragma unroll
    for (int fm = 0; fm < 10; ++fm) {
      int rp = rpA + fm * 8;
      aoff[fm] = rp * 128 + (((odA | lk) ^ (rp & 7)) * 16);
    }
    int rowB = wn * 80 + lrow;
    int rpB = rowB >> 1, odB = (rowB & 1) << 2;
#pragma unroll
    for (int fn = 0; fn < 5; ++fn) {
      int rp = rpB + fn * 8;
      boff[fn] = 20480 + rp * 128 + (((odB | lk) ^ (rp & 7)) * 16);
    }
  }

  f32x4 acc[10][5];
#pragma unroll
  for (int i = 0; i < 10; ++i)
#pragma unroll
    for (int j = 0; j < 5; ++j) acc[i][j] = (f32x4){0.f, 0.f, 0.f, 0.f};

  STG320(0, 0); STG320(1, 1);
  WAITV(5);
  SB; BAR; SB;

  for (int t = 0; t < 32; ++t) {
    const int cb = t % 3;
    if (t + 2 < 32) STG320(t + 2, (t + 2) % 3);
    const char* Ab = smem + cb * 40960;
    s16x8 bR[5];
#pragma unroll
    for (int fn = 0; fn < 5; ++fn) bR[fn] = *(const s16x8*)(Ab + boff[fn]);
#pragma unroll
    for (int fm = 0; fm < 10; ++fm) {
      s16x8 aT = *(const s16x8*)(Ab + aoff[fm]);
#pragma unroll
      for (int fn = 0; fn < 5; ++fn)
        acc[fm][fn] = __builtin_amdgcn_mfma_f32_16x16x32_bf16(
            aT, bR[fn], acc[fm][fn], 0, 0, 0);
    }
    if (t + 2 < 32) { WAITV(5); }
    else if (t == 30) { WAITV(0); }
    SB; BAR; SB;
  }
#undef STG320

  const int crow = l >> 4, ccol = l & 15;
#pragma unroll
  for (int fm = 0; fm < 10; ++fm)
#pragma unroll
    for (int fn = 0; fn < 5; ++fn) {
      size_t rb = (size_t)(row0 + wm * 160 + fm * 16 + crow * 4);
      int col = col0 + wn * 80 + fn * 16 + ccol;
#pragma unroll
      for (int r = 0; r < 4; ++r)
        C[(rb + r) * ldc + col] = f2bf(acc[fm][fn][r]);
    }
}

// ---------- out GEMM: 160x256 tile, 256 blocks = 1 full-resident round ------
// R14-proven. C fp32 = A @ Bt^T. 8 waves (2M x 4N), wave tile 80x64.
__global__ __launch_bounds__(512, 2) void gemm_out(
    const u16* __restrict__ A, const u16* __restrict__ Bt,
    float* __restrict__ C, int ldc)
{
  extern __shared__ __align__(16) char smem[];   // 3 x 26624 = 79872 B
  const int tid = threadIdx.x;
  const int l   = tid & 63;
  const int wid = tid >> 6;
  const int wm  = wid >> 2;
  const int wn  = wid & 3;
  const int row0 = blockIdx.x * 160;
  const int col0 = blockIdx.y * 256;

  const u16* gsrc[4];
  bool gact[4];
#pragma unroll
  for (int j = 0; j < 4; ++j) {
    int c = j * 512 + tid;
    gact[j] = (c < 1664);
    int cc = gact[j] ? c : 0;
    int mc = (cc < 640) ? cc : cc - 640;
    int rp = mc >> 3, s = mc & 7, gs = s ^ (rp & 7);
    int grow = rp * 2 + (gs >> 2), gk = (gs & 3) * 8;
    gsrc[j] = (cc < 640) ? (A + (size_t)(row0 + grow) * 1024 + gk)
                         : (Bt + (size_t)(col0 + grow) * 1024 + gk);
  }

#define STGO(tt, bb) do {                                                     \
    _Pragma("unroll")                                                         \
    for (int j_ = 0; j_ < 4; ++j_)                                            \
      if (gact[j_])                                                           \
        ASYNC16(gsrc[j_] + (tt) * 32,                                         \
                smem + (bb) * 26624 + (j_ * 512 + tid) * 16);                 \
  } while (0)

  const int lrow = l & 15, lk = l >> 4;
  int aoff[5], boff[4];
  {
    int rowA = wm * 80 + lrow;
    int rpA = rowA >> 1, odA = (rowA & 1) << 2;
#pragma unroll
    for (int fm = 0; fm < 5; ++fm) {
      int rp = rpA + fm * 8;
      aoff[fm] = rp * 128 + (((odA | lk) ^ (rp & 7)) * 16);
    }
    int rowB = wn * 64 + lrow;
    int rpB = rowB >> 1, odB = (rowB & 1) << 2;
#pragma unroll
    for (int fn = 0; fn < 4; ++fn) {
      int rp = rpB + fn * 8;
      boff[fn] = 10240 + rp * 128 + (((odB | lk) ^ (rp & 7)) * 16);
    }
  }

  f32x4 acc[5][4];
#pragma unroll
  for (int i = 0; i < 5; ++i)
#pragma unroll
    for (int j = 0; j < 4; ++j) acc[i][j] = (f32x4){0.f, 0.f, 0.f, 0.f};

  STGO(0, 0); STGO(1, 1);
  WAITV(3);
  SB; BAR; SB;

  for (int t = 0; t < 32; ++t) {
    const int cb = t % 3;
    if (t + 2 < 32) STGO(t + 2, (t + 2) % 3);
    const char* Ab = smem + cb * 26624;
    s16x8 bR[4];
#pragma unroll
    for (int fn = 0; fn < 4; ++fn) bR[fn] = *(const s16x8*)(Ab + boff[fn]);
#pragma unroll
    for (int fm = 0; fm < 5; ++fm) {
      s16x8 aT = *(const s16x8*)(Ab + aoff[fm]);
#pragma unroll
      for (int fn = 0; fn < 4; ++fn)
        acc[fm][fn] = __builtin_amdgcn_mfma_f32_16x16x32_bf16(
            aT, bR[fn], acc[fm][fn], 0, 0, 0);
    }
    if (t + 2 < 32) { WAITV(3); }
    else if (t == 30) { WAITV(0); }
    SB; BAR; SB;
  }
#undef STGO

  const int crow = l >> 4, ccol = l & 15;
#pragma unroll
  for (int fm = 0; fm < 5; ++fm)
#pragma unroll
    for (int fn = 0; fn < 4; ++fn) {
      size_t rb = (size_t)(row0 + wm * 80 + fm * 16 + crow * 4);
      int col = col0 + wn * 64 + fn * 16 + ccol;
#pragma unroll
      for (int r = 0; r < 4; ++r)
        C[(rb + r) * ldc + col] = acc[fm][fn][r];
    }
}

// ---------- deltas = q2view[8192][1280] @ dwbf^T + db -----------------------
// R16: 256 blocks (full chip) x 128 threads (2 waves), 32-row tiles.
// 4-buffer staged pipeline, 3 loads/thread/unit, counted WAITV(6).
__global__ __launch_bounds__(128) void delta_mfma(
    const u16* __restrict__ proj, const u16* __restrict__ dwbf,
    const float* __restrict__ db, float* __restrict__ deltas)
{
  __shared__ __align__(16) u16 As[4][32 * 32];   // 2 KB each
  __shared__ __align__(16) u16 Bs[4][64 * 32];   // 4 KB each
  const int tid  = threadIdx.x;
  const int lane = tid & 63;
  const int w    = tid >> 6;        // 0..1
  const int row0 = blockIdx.x * 32;
  const int wr   = w * 16;
  const int lrow = lane & 15;
  const int lk   = lane >> 4;

  f32x4 acc[4];
#pragma unroll
  for (int j = 0; j < 4; ++j) acc[j] = (f32x4){0.f, 0.f, 0.f, 0.f};

  // A: 128 chunks (32 rows x 4 kslots), 1/thread. q2 flat i -> proj view.
  const size_t lin0 = (size_t)(row0 + (tid >> 2)) * 1280 + (tid & 3) * 8;
  // B: 256 chunks (64 rows x 4 kslots), 2/thread (c = j*128 + tid).
  const u16* Bg0 = dwbf + (size_t)(tid >> 2) * 1280 + (tid & 3) * 8;
  const u16* Bg1 = dwbf + (size_t)((128 + tid) >> 2) * 1280 + (tid & 3) * 8;

#define STD(kk, bb) do {                                                      \
    size_t lin_ = lin0 + (kk) * 32;                                           \
    ASYNC16(proj + (lin_ >> 10) * 5120 + (lin_ & 1023),                       \
            (char*)As + (bb) * 2048 + tid * 16);                              \
    ASYNC16(Bg0 + (kk) * 32, (char*)Bs + (bb) * 4096 + tid * 16);             \
    ASYNC16(Bg1 + (kk) * 32, (char*)Bs + (bb) * 4096 + (128 + tid) * 16);     \
  } while (0)

  const int aoff = (wr + lrow) * 64 + lk * 16;
  int boff[4];
#pragma unroll
  for (int f = 0; f < 4; ++f) boff[f] = (f * 16 + lrow) * 64 + lk * 16;

  // prologue: chunks 0..2 -> bufs 0..2 (9 loads); chunk 0 landed at vmcnt(6)
  STD(0, 0); STD(1, 1); STD(2, 2);
  WAITV(6);
  SB; BAR; SB;

  for (int k = 0; k < 40; ++k) {
    const int bb = k & 3;
    if (k + 3 < 40) STD(k + 3, (k + 3) & 3);   // buf read at k-1: WAR-safe
    s16x8 af = *(const s16x8*)((const char*)As + bb * 2048 + aoff);
#pragma unroll
    for (int fn = 0; fn < 4; ++fn) {
      s16x8 bfr = *(const s16x8*)((const char*)Bs + bb * 4096 + boff[fn]);
      acc[fn] = __builtin_amdgcn_mfma_f32_16x16x32_bf16(af, bfr, acc[fn], 0, 0, 0);
    }
    if (k < 37)      { WAITV(6); }
    else if (k == 37){ WAITV(3); }
    else if (k == 38){ WAITV(0); }
    SB; BAR; SB;
  }
#undef STD

  const int crow = lane >> 4;
  const int ccol = lane & 15;
#pragma unroll
  for (int fn = 0; fn < 4; ++fn) {
    int col = fn * 16 + ccol;
    if (col < 60) {
      float d = db[col];
      size_t rb = (size_t)(row0 + wr + crow * 4);
#pragma unroll
      for (int r = 0; r < 4; ++r)
        deltas[(rb + r) * 60 + col] = acc[fn][r] + d;
    }
  }
}

// ---------- coords: pd = ref + deltas ; L2-normalize over the hi axis -------
__global__ void coords_kernel(const float* __restrict__ deltas,
                              float* __restrict__ vgx, float* __restrict__ vgy)
{
  int g = blockIdx.x * 256 + threadIdx.x;
  if (g >= 32 * 16 * 10 * 3) return;
  int kk = g % 3, tmp = g / 3;
  int s = tmp % 10; tmp /= 10;
  int wi = tmp % 16; int bnm = tmp / 16;
  float gxr = wi * (1.0f / 15.0f);
  float px[16], py[16];
  float sx = 0.f, sy = 0.f;
#pragma unroll
  for (int hi = 0; hi < 16; ++hi) {
    size_t base = ((size_t)((bnm * 16 + hi) * 16 + wi)) * 60 + (s * 3 + kk) * 2;
    float x = gxr + deltas[base];
    float y = hi * (1.0f / 15.0f) + deltas[base + 1];
    px[hi] = x; py[hi] = y;
    sx += x * x; sy += y * y;
  }
  float rx = 1.0f / fmaxf(sqrtf(sx), 1e-12f);
  float ry = 1.0f / fmaxf(sqrtf(sy), 1e-12f);
#pragma unroll
  for (int hi = 0; hi < 16; ++hi) {
    size_t o = ((size_t)((bnm * 16 + hi) * 16 + wi) * 10 + s) * 3 + kk;
    vgx[o] = px[hi] * rx;
    vgy[o] = py[hi] * ry;
  }
}

// ---------- MFMA attention (R9 version, measured-best) ----------------------
__global__ __launch_bounds__(256) void attn_mfma(
    const u16* __restrict__ proj, const float* __restrict__ vgx,
    const float* __restrict__ vgy, u16* __restrict__ headf,
    float* __restrict__ attn0)
{
  const int bid = blockIdx.x;
  const int m = bid >> 10, b = bid & 1023;
  const int tid = threadIdx.x;
  const int lane = tid & 63;
  const int w = tid >> 6;

  __shared__ __align__(16) u16 ksb[32][136];
  __shared__ __align__(16) u16 vt[128][32];
  __shared__ __align__(16) u16 pl[16][40];
  __shared__ float wst[30][4];
  __shared__ int   cst[30][4];

  s16x8 aq[4];
  if (w == 0) {
    size_t linb = (size_t)bid * 1280 + (size_t)(lane & 15) * 128 + (lane >> 4) * 8;
#pragma unroll
    for (int kk = 0; kk < 4; ++kk) {
      size_t lin = linb + kk * 32;
      aq[kk] = *(const s16x8*)(proj + (lin >> 10) * 5120 + (lin & 1023));
    }
  }

  if (tid < 30) {
    int t = tid, kk = t / 10, sk = t % 10;
    size_t ci = ((size_t)bid * 10 + sk) * 3 + kk;
    float gx = vgx[ci], gy = vgy[ci];
    float ix = (gx + 1.0f) * 8.0f - 0.5f;
    float iy = (gy + 1.0f) * 8.0f - 0.5f;
    float x0f = floorf(ix), y0f = floorf(iy);
    float wx1 = ix - x0f, wx0 = 1.0f - wx1;
    float wy1 = iy - y0f, wy0 = 1.0f - wy1;
    float x1f = x0f + 1.0f, y1f = y0f + 1.0f;
    bool vx0 = (x0f >= 0.f) && (x0f <= 15.f);
    bool vx1 = (x1f >= 0.f) && (x1f <= 15.f);
    bool vy0 = (y0f >= 0.f) && (y0f <= 15.f);
    bool vy1 = (y1f >= 0.f) && (y1f <= 15.f);
    int x0 = min(max((int)x0f, 0), 15);
    int x1 = min(max((int)x1f, 0), 15);
    int y0 = min(max((int)y0f, 0), 15);
    int y1 = min(max((int)y1f, 0), 15);
    wst[t][0] = wx0 * wy0 * ((vx0 && vy0) ? 1.f : 0.f);
    wst[t][1] = wx1 * wy0 * ((vx1 && vy0) ? 1.f : 0.f);
    wst[t][2] = wx0 * wy1 * ((vx0 && vy1) ? 1.f : 0.f);
    wst[t][3] = wx1 * wy1 * ((vx1 && vy1) ? 1.f : 0.f);
    cst[t][0] = x0; cst[t][1] = x1; cst[t][2] = y0; cst[t][3] = y1;
  }
  __syncthreads();

  for (int i = tid; i < 512; i += 256) {
    int t = i & 31, c = i >> 5;
    u16x8 v = (u16x8){0, 0, 0, 0, 0, 0, 0, 0};
    if (t < 30) {
      int sv = t / 3, cv = t - sv * 3;
      v = *(const u16x8*)(proj + ((size_t)(b * 10 + sv)) * 5120 + 2048 +
                          m * 384 + cv * 128 + c * 8);
    }
#pragma unroll
    for (int r = 0; r < 8; ++r)
      vt[8 * c + r][t ^ (8 * (r & 3))] = v[r];
  }

  {
    int pb = (b >> 8) << 8;
    for (int i = tid; i < 480; i += 256) {
      int t = i >> 4, c = i & 15;
      int sk = t % 10;
      int x0 = cst[t][0], x1 = cst[t][1], y0 = cst[t][2], y1 = cst[t][3];
      float w00 = wst[t][0], w10 = wst[t][1], w01 = wst[t][2], w11 = wst[t][3];
      size_t colo = 1024 + (size_t)m * 128 + c * 8;
      const u16x8 f00 = *(const u16x8*)&proj[((size_t)((pb + y0 * 16 + x0) * 10 + sk)) * 5120 + colo];
      const u16x8 f10 = *(const u16x8*)&proj[((size_t)((pb + y0 * 16 + x1) * 10 + sk)) * 5120 + colo];
      const u16x8 f01 = *(const u16x8*)&proj[((size_t)((pb + y1 * 16 + x0) * 10 + sk)) * 5120 + colo];
      const u16x8 f11 = *(const u16x8*)&proj[((size_t)((pb + y1 * 16 + x1) * 10 + sk)) * 5120 + colo];
      u16x8 o;
#pragma unroll
      for (int r = 0; r < 8; ++r) {
        float acc = w00 * bf2f(f00[r]) + w10 * bf2f(f10[r]) +
                    w01 * bf2f(f01[r]) + w11 * bf2f(f11[r]);
        o[r] = f2bf(acc);
      }
      *(u16x8*)&ksb[t][c * 8] = o;
    }
  }
  __syncthreads();

  if (w == 0) {
    f32x4 dq[2];
    dq[0] = (f32x4){0.f, 0.f, 0.f, 0.f};
    dq[1] = (f32x4){0.f, 0.f, 0.f, 0.f};
    const int lr = lane & 15, g = lane >> 4;
#pragma unroll
    for (int kk = 0; kk < 4; ++kk) {
      s16x8 b0 = *(const s16x8*)&ksb[lr][g * 8 + kk * 32];
      s16x8 b1 = *(const s16x8*)&ksb[16 + lr][g * 8 + kk * 32];
      dq[0] = __builtin_amdgcn_mfma_f32_16x16x32_bf16(aq[kk], b0, dq[0], 0, 0, 0);
      dq[1] = __builtin_amdgcn_mfma_f32_16x16x32_bf16(aq[kk], b1, dq[1], 0, 0, 0);
    }
    float p[2][4];
#pragma unroll
    for (int f = 0; f < 2; ++f) {
      int t = lr + 16 * f;
#pragma unroll
      for (int r = 0; r < 4; ++r) {
        float v = dq[f][r] * 0.08838834764831845f;
        p[f][r] = (t < 30) ? v : -1e30f;
      }
    }
#pragma unroll
    for (int r = 0; r < 4; ++r) {
      float mx = fmaxf(p[0][r], p[1][r]);
#pragma unroll
      for (int msk = 1; msk <= 8; msk <<= 1) mx = fmaxf(mx, __shfl_xor(mx, msk));
      float e0 = __expf(p[0][r] - mx);
      float e1 = __expf(p[1][r] - mx);
      float sm = e0 + e1;
#pragma unroll
      for (int msk = 1; msk <= 8; msk <<= 1) sm += __shfl_xor(sm, msk);
      float inv = 1.0f / sm;
      p[0][r] = e0 * inv;
      p[1][r] = e1 * inv;
    }
    if (g == 0) {
      attn0[(size_t)bid * 30 + lr] = p[0][0];
      if (lr < 14) attn0[(size_t)bid * 30 + 16 + lr] = p[1][0];
    }
#pragma unroll
    for (int f = 0; f < 2; ++f)
#pragma unroll
      for (int r = 0; r < 4; ++r)
        pl[g * 4 + r][lr + 16 * f] = f2bf(p[f][r]);
  }
  __syncthreads();

  const int lr = lane & 15, g = lane >> 4;
  s16x8 pa = *(const s16x8*)&pl[lr][g * 8];
#pragma unroll
  for (int qf = 0; qf < 2; ++qf) {
    int fv = w * 2 + qf;
    int v = fv * 16 + lr;
    s16x8 bv = *(const s16x8*)&vt[v][8 * (g ^ (v & 3))];
    f32x4 acc = (f32x4){0.f, 0.f, 0.f, 0.f};
    acc = __builtin_amdgcn_mfma_f32_16x16x32_bf16(pa, bv, acc, 0, 0, 0);
#pragma unroll
    for (int r = 0; r < 4; ++r) {
      int s = g * 4 + r;
      if (s < 10)
        headf[((size_t)(b * 10 + s)) * 1024 + m * 128 + v] = f2bf(acc[r]);
    }
  }
}

// ---------- attn_map[b][t] = mean_m attn0[m][b][t] --------------------------
__global__ void attnmap_kernel(const float* __restrict__ attn0, float* __restrict__ outa)
{
  int i = blockIdx.x * 256 + threadIdx.x;
  if (i >= 30720) return;
  int b = i / 30, t = i % 30;
  float s = 0.f;
  for (int mm = 0; mm < 8; ++mm) s += attn0[((size_t)mm * 1024 + b) * 30 + t];
  outa[i] = 0.125f * s;
}

// ---------------------------------------------------------------------------
extern "C" void kernel_launch(void* const* d_in, const int* in_sizes, int n_in,
                              void* d_out, int out_size, void* d_ws, size_t ws_size,
                              hipStream_t stream)
{
  const float* q  = (const float*)d_in[0];
  const float* Wq = (const float*)d_in[1];
  const float* Wk = (const float*)d_in[2];
  const float* Wv = (const float*)d_in[3];
  const float* Wo = (const float*)d_in[4];
  const float* dw = (const float*)d_in[5];
  const float* db = (const float*)d_in[6];
  float* out = (float*)d_out;
  float* attn_out = out + 10485760;

  // workspace layout (bytes): total ~165 MB. Wcat MUST follow Abf.
  char* p = (char*)d_ws;
  u16*   Abf   = (u16*)p;   p += 20971520;    // [10240][1024] bf16
  u16*   Wcat  = (u16*)p;   p += 12582912;    // [6144][1024] bf16 (B^T fused)
  u16*   proj  = (u16*)p;   p += 104857600;   // [10240][5120] bf16 (q2|kp|vp)
  u16*   headf = (u16*)p;   p += 20971520;    // [10240][1024] bf16
  u16*   dwbf  = (u16*)p;   p += 163840;      // [64][1280] bf16
  float* dels  = (float*)p; p += 1966080;     // [8192][60]
  float* vgxp  = (float*)p; p += 983040;
  float* vgyp  = (float*)p; p += 983040;
  float* attn0 = (float*)p; p += 983040;

  conv_a<<<dim3(5120), dim3(256), 0, stream>>>(q, Abf, 1310720);
  conv_w<<<dim3(3072), dim3(256), 0, stream>>>(Wq, Wk, Wv, Wo, Wcat);
  conv_dw<<<dim3(40), dim3(256), 0, stream>>>(dw, dwbf);

  // fused projections: proj = Abf @ Wcat[0:5120]^T; 512 blocks = 2 rounds
  gemm_320<<<dim3(32, 16), dim3(512), 122880, stream>>>(
      Abf, 10485760L, proj, 5120);

  delta_mfma<<<dim3(256), dim3(128), 0, stream>>>(proj, dwbf, db, dels);
  coords_kernel<<<dim3(60), dim3(256), 0, stream>>>(dels, vgxp, vgyp);
  attn_mfma<<<dim3(8192), dim3(256), 0, stream>>>(proj, vgxp, vgyp, headf, attn0);
  attnmap_kernel<<<dim3(120), dim3(256), 0, stream>>>(attn0, attn_out);

  // out = headf @ Wo^T (Wcat rows 5120..6143); 64x4 = 256 blocks = 1 round
  gemm_out<<<dim3(64, 4), dim3(512), 79872, stream>>>(
      headf, Wcat + (size_t)5120 * 1024, out, 1024);
}

// Round 17
// 232.992 us; speedup vs baseline: 4.6542x; 1.0057x over previous
//
#include <hip/hip_runtime.h>

// ---------------------------------------------------------------------------
// MultiHeadAttention_50646254354439 — R17: R16 (best, 234.3us) + XCD-chunked
// bid swizzle in attn_mfma (each XCD owns one head m -> kp gather slice
// 2.6 MB L2-resident; default round-robin caused ~8x gather re-fetch).
// Dims: B=1024,S=10,D=1024,E=1024,V=KD=128,H=M=8,K=3,HI=WI=16. N=10240.
// proj=[10240][5120] bf16 = q2|kp|vp fused.
// ---------------------------------------------------------------------------

typedef float    f32x4 __attribute__((ext_vector_type(4)));
typedef short    s16x8 __attribute__((ext_vector_type(8)));
typedef unsigned short u16x8 __attribute__((ext_vector_type(8)));
typedef unsigned short u16;

__device__ __forceinline__ u16 f2bf(float f) {   // RNE float->bf16
  union { float f; unsigned u; } x; x.f = f;
  unsigned r = x.u + 0x7FFFu + ((x.u >> 16) & 1u);
  return (u16)(r >> 16);
}
__device__ __forceinline__ float bf2f(u16 u) {
  union { unsigned u; float f; } x; x.u = ((unsigned)u) << 16;
  return x.f;
}

#define ASYNC16(g, l) __builtin_amdgcn_global_load_lds(                       \
    (const __attribute__((address_space(1))) void*)(g),                       \
    (__attribute__((address_space(3))) void*)(l), 16, 0, 0)
#define WAITV(n) asm volatile("s_waitcnt vmcnt(" #n ")" ::: "memory")
#define WAITL    asm volatile("s_waitcnt lgkmcnt(0)" ::: "memory")
#define SB       __builtin_amdgcn_sched_barrier(0)
#define BAR      __builtin_amdgcn_s_barrier()

// ---------- fp32 -> bf16 elementwise ----------------------------------------
__global__ __launch_bounds__(256) void conv_a(
    const float* __restrict__ src, u16* __restrict__ dst, int n8)
{
  int i = blockIdx.x * 256 + threadIdx.x;
  if (i >= n8) return;
  const float4* s = (const float4*)src + (size_t)i * 2;
  float4 a = s[0], b = s[1];
  u16x8 o;
  o[0] = f2bf(a.x); o[1] = f2bf(a.y); o[2] = f2bf(a.z); o[3] = f2bf(a.w);
  o[4] = f2bf(b.x); o[5] = f2bf(b.y); o[6] = f2bf(b.z); o[7] = f2bf(b.w);
  *(u16x8*)(dst + (size_t)i * 8) = o;
}

// ---------- build fused B^T (K-contiguous) weight matrix, bf16 --------------
__global__ __launch_bounds__(256) void conv_w(
    const float* __restrict__ Wq, const float* __restrict__ Wk,
    const float* __restrict__ Wv, const float* __restrict__ Wo,
    u16* __restrict__ Wcat)
{
  int i = blockIdx.x * 256 + threadIdx.x;   // 6144*128 = 786432 threads
  if (i >= 6144 * 128) return;
  int c = i >> 7;
  int d0 = (i & 127) * 8;
  const float* src; int stride;
  if (c < 1024)      { int kq = c >> 3, h = c & 7;
                       src = Wq + (size_t)h * 131072 + kq;      stride = 128; }
  else if (c < 2048) { int j = c - 1024; int h = j >> 7, k = j & 127;
                       src = Wk + (size_t)h * 131072 + k;       stride = 128; }
  else if (c < 5120) { int j = c - 2048; int h = j / 384, cc = j - h * 384;
                       src = Wv + (size_t)h * 393216 + cc;      stride = 384; }
  else               { int e = c - 5120;
                       src = Wo + e;                            stride = 1024; }
  u16x8 o;
#pragma unroll
  for (int r = 0; r < 8; ++r) o[r] = f2bf(src[(size_t)(d0 + r) * stride]);
  *(u16x8*)(Wcat + (size_t)c * 1024 + d0) = o;
}

// ---------- dw -> bf16 [64][1280] (rows >=60 dummy=row0, never written) -----
__global__ __launch_bounds__(256) void conv_dw(
    const float* __restrict__ dw, u16* __restrict__ dwbf)
{
  int i = blockIdx.x * 256 + threadIdx.x;   // 64*160 = 10240 chunks
  if (i >= 10240) return;
  int row = i / 160, ch = i - row * 160;
  int srow = (row < 60) ? row : 0;
  const float4* s = (const float4*)(dw + (size_t)srow * 1280 + ch * 8);
  float4 a = s[0], b = s[1];
  u16x8 o;
  o[0] = f2bf(a.x); o[1] = f2bf(a.y); o[2] = f2bf(a.z); o[3] = f2bf(a.w);
  o[4] = f2bf(b.x); o[5] = f2bf(b.y); o[6] = f2bf(b.z); o[7] = f2bf(b.w);
  *(u16x8*)(dwbf + (size_t)row * 1280 + ch * 8) = o;
}

// ---------- 320x320 bf16 MFMA GEMM (proj): C = A @ Bt^T ---------------------
// R9/R14-proven: 512 blocks = 2 exact rounds, triple-buffered 40KB units,
// counted vmcnt(5), one barrier/tile. DO NOT add register state (R11/R15).
__global__ __launch_bounds__(512, 2) void gemm_320(
    const u16* __restrict__ base, long bOff, u16* __restrict__ C, int ldc)
{
  extern __shared__ __align__(16) char smem[];   // 3 x 40960 = 122880 B
  const int tid = threadIdx.x;
  const int l   = tid & 63;
  const int wid = tid >> 6;
  const int wm  = wid >> 2;
  const int wn  = wid & 3;
  const int row0 = blockIdx.x * 320;
  const int col0 = blockIdx.y * 320;

  int eoff[5];
#pragma unroll
  for (int j = 0; j < 5; ++j) {
    int c = j * 512 + tid;
    int mc = (c < 1280) ? c : c - 1280;
    int rp = mc >> 3, s = mc & 7, gs = s ^ (rp & 7);
    int grow = rp * 2 + (gs >> 2), gk = (gs & 3) * 8;
    eoff[j] = (c < 1280) ? ((row0 + grow) * 1024 + gk)
                         : (int)(bOff + (size_t)(col0 + grow) * 1024 + gk);
  }

#define STG320(tt, bb) do {                                                   \
    _Pragma("unroll")                                                         \
    for (int j_ = 0; j_ < 5; ++j_)                                            \
      ASYNC16(base + eoff[j_] + (tt) * 32,                                    \
              smem + (bb) * 40960 + (j_ * 512 + tid) * 16);                   \
  } while (0)

  const int lrow = l & 15, lk = l >> 4;
  int aoff[10], boff[5];
  {
    int rowA = wm * 160 + lrow;
    int rpA = rowA >> 1, odA = (rowA & 1) << 2;
#pragma unroll
    for (int fm = 0; fm < 10; ++fm) {
      int rp = rpA + fm * 8;
      aoff[fm] = rp * 128 + (((odA | lk) ^ (rp & 7)) * 16);
    }
    int rowB = wn * 80 + lrow;
    int rpB = rowB >> 1, odB = (rowB & 1) << 2;
#pragma unroll
    for (int fn = 0; fn < 5; ++fn) {
      int rp = rpB + fn * 8;
      boff[fn] = 20480 + rp * 128 + (((odB | lk) ^ (rp & 7)) * 16);
    }
  }

  f32x4 acc[10][5];
#pragma unroll
  for (int i = 0; i < 10; ++i)
#pragma unroll
    for (int j = 0; j < 5; ++j) acc[i][j] = (f32x4){0.f, 0.f, 0.f, 0.f};

  STG320(0, 0); STG320(1, 1);
  WAITV(5);
  SB; BAR; SB;

  for (int t = 0; t < 32; ++t) {
    const int cb = t % 3;
    if (t + 2 < 32) STG320(t + 2, (t + 2) % 3);
    const char* Ab = smem + cb * 40960;
    s16x8 bR[5];
#pragma unroll
    for (int fn = 0; fn < 5; ++fn) bR[fn] = *(const s16x8*)(Ab + boff[fn]);
#pragma unroll
    for (int fm = 0; fm < 10; ++fm) {
      s16x8 aT = *(const s16x8*)(Ab + aoff[fm]);
#pragma unroll
      for (int fn = 0; fn < 5; ++fn)
        acc[fm][fn] = __builtin_amdgcn_mfma_f32_16x16x32_bf16(
            aT, bR[fn], acc[fm][fn], 0, 0, 0);
    }
    if (t + 2 < 32) { WAITV(5); }
    else if (t == 30) { WAITV(0); }
    SB; BAR; SB;
  }
#undef STG320

  const int crow = l >> 4, ccol = l & 15;
#pragma unroll
  for (int fm = 0; fm < 10; ++fm)
#pragma unroll
    for (int fn = 0; fn < 5; ++fn) {
      size_t rb = (size_t)(row0 + wm * 160 + fm * 16 + crow * 4);
      int col = col0 + wn * 80 + fn * 16 + ccol;
#pragma unroll
      for (int r = 0; r < 4; ++r)
        C[(rb + r) * ldc + col] = f2bf(acc[fm][fn][r]);
    }
}

// ---------- out GEMM: 160x256 tile, 256 blocks = 1 full-resident round ------
// R14-proven. C fp32 = A @ Bt^T. 8 waves (2M x 4N), wave tile 80x64.
__global__ __launch_bounds__(512, 2) void gemm_out(
    const u16* __restrict__ A, const u16* __restrict__ Bt,
    float* __restrict__ C, int ldc)
{
  extern __shared__ __align__(16) char smem[];   // 3 x 26624 = 79872 B
  const int tid = threadIdx.x;
  const int l   = tid & 63;
  const int wid = tid >> 6;
  const int wm  = wid >> 2;
  const int wn  = wid & 3;
  const int row0 = blockIdx.x * 160;
  const int col0 = blockIdx.y * 256;

  const u16* gsrc[4];
  bool gact[4];
#pragma unroll
  for (int j = 0; j < 4; ++j) {
    int c = j * 512 + tid;
    gact[j] = (c < 1664);
    int cc = gact[j] ? c : 0;
    int mc = (cc < 640) ? cc : cc - 640;
    int rp = mc >> 3, s = mc & 7, gs = s ^ (rp & 7);
    int grow = rp * 2 + (gs >> 2), gk = (gs & 3) * 8;
    gsrc[j] = (cc < 640) ? (A + (size_t)(row0 + grow) * 1024 + gk)
                         : (Bt + (size_t)(col0 + grow) * 1024 + gk);
  }

#define STGO(tt, bb) do {                                                     \
    _Pragma("unroll")                                                         \
    for (int j_ = 0; j_ < 4; ++j_)                                            \
      if (gact[j_])                                                           \
        ASYNC16(gsrc[j_] + (tt) * 32,                                         \
                smem + (bb) * 26624 + (j_ * 512 + tid) * 16);                 \
  } while (0)

  const int lrow = l & 15, lk = l >> 4;
  int aoff[5], boff[4];
  {
    int rowA = wm * 80 + lrow;
    int rpA = rowA >> 1, odA = (rowA & 1) << 2;
#pragma unroll
    for (int fm = 0; fm < 5; ++fm) {
      int rp = rpA + fm * 8;
      aoff[fm] = rp * 128 + (((odA | lk) ^ (rp & 7)) * 16);
    }
    int rowB = wn * 64 + lrow;
    int rpB = rowB >> 1, odB = (rowB & 1) << 2;
#pragma unroll
    for (int fn = 0; fn < 4; ++fn) {
      int rp = rpB + fn * 8;
      boff[fn] = 10240 + rp * 128 + (((odB | lk) ^ (rp & 7)) * 16);
    }
  }

  f32x4 acc[5][4];
#pragma unroll
  for (int i = 0; i < 5; ++i)
#pragma unroll
    for (int j = 0; j < 4; ++j) acc[i][j] = (f32x4){0.f, 0.f, 0.f, 0.f};

  STGO(0, 0); STGO(1, 1);
  WAITV(3);
  SB; BAR; SB;

  for (int t = 0; t < 32; ++t) {
    const int cb = t % 3;
    if (t + 2 < 32) STGO(t + 2, (t + 2) % 3);
    const char* Ab = smem + cb * 26624;
    s16x8 bR[4];
#pragma unroll
    for (int fn = 0; fn < 4; ++fn) bR[fn] = *(const s16x8*)(Ab + boff[fn]);
#pragma unroll
    for (int fm = 0; fm < 5; ++fm) {
      s16x8 aT = *(const s16x8*)(Ab + aoff[fm]);
#pragma unroll
      for (int fn = 0; fn < 4; ++fn)
        acc[fm][fn] = __builtin_amdgcn_mfma_f32_16x16x32_bf16(
            aT, bR[fn], acc[fm][fn], 0, 0, 0);
    }
    if (t + 2 < 32) { WAITV(3); }
    else if (t == 30) { WAITV(0); }
    SB; BAR; SB;
  }
#undef STGO

  const int crow = l >> 4, ccol = l & 15;
#pragma unroll
  for (int fm = 0; fm < 5; ++fm)
#pragma unroll
    for (int fn = 0; fn < 4; ++fn) {
      size_t rb = (size_t)(row0 + wm * 80 + fm * 16 + crow * 4);
      int col = col0 + wn * 64 + fn * 16 + ccol;
#pragma unroll
      for (int r = 0; r < 4; ++r)
        C[(rb + r) * ldc + col] = acc[fm][fn][r];
    }
}

// ---------- deltas = q2view[8192][1280] @ dwbf^T + db -----------------------
// R16-proven: 256 blocks (full chip) x 128 threads, 32-row tiles, WAITV(6).
__global__ __launch_bounds__(128) void delta_mfma(
    const u16* __restrict__ proj, const u16* __restrict__ dwbf,
    const float* __restrict__ db, float* __restrict__ deltas)
{
  __shared__ __align__(16) u16 As[4][32 * 32];
  __shared__ __align__(16) u16 Bs[4][64 * 32];
  const int tid  = threadIdx.x;
  const int lane = tid & 63;
  const int w    = tid >> 6;
  const int row0 = blockIdx.x * 32;
  const int wr   = w * 16;
  const int lrow = lane & 15;
  const int lk   = lane >> 4;

  f32x4 acc[4];
#pragma unroll
  for (int j = 0; j < 4; ++j) acc[j] = (f32x4){0.f, 0.f, 0.f, 0.f};

  const size_t lin0 = (size_t)(row0 + (tid >> 2)) * 1280 + (tid & 3) * 8;
  const u16* Bg0 = dwbf + (size_t)(tid >> 2) * 1280 + (tid & 3) * 8;
  const u16* Bg1 = dwbf + (size_t)((128 + tid) >> 2) * 1280 + (tid & 3) * 8;

#define STD(kk, bb) do {                                                      \
    size_t lin_ = lin0 + (kk) * 32;                                           \
    ASYNC16(proj + (lin_ >> 10) * 5120 + (lin_ & 1023),                       \
            (char*)As + (bb) * 2048 + tid * 16);                              \
    ASYNC16(Bg0 + (kk) * 32, (char*)Bs + (bb) * 4096 + tid * 16);             \
    ASYNC16(Bg1 + (kk) * 32, (char*)Bs + (bb) * 4096 + (128 + tid) * 16);     \
  } while (0)

  const int aoff = (wr + lrow) * 64 + lk * 16;
  int boff[4];
#pragma unroll
  for (int f = 0; f < 4; ++f) boff[f] = (f * 16 + lrow) * 64 + lk * 16;

  STD(0, 0); STD(1, 1); STD(2, 2);
  WAITV(6);
  SB; BAR; SB;

  for (int k = 0; k < 40; ++k) {
    const int bb = k & 3;
    if (k + 3 < 40) STD(k + 3, (k + 3) & 3);
    s16x8 af = *(const s16x8*)((const char*)As + bb * 2048 + aoff);
#pragma unroll
    for (int fn = 0; fn < 4; ++fn) {
      s16x8 bfr = *(const s16x8*)((const char*)Bs + bb * 4096 + boff[fn]);
      acc[fn] = __builtin_amdgcn_mfma_f32_16x16x32_bf16(af, bfr, acc[fn], 0, 0, 0);
    }
    if (k < 37)      { WAITV(6); }
    else if (k == 37){ WAITV(3); }
    else if (k == 38){ WAITV(0); }
    SB; BAR; SB;
  }
#undef STD

  const int crow = lane >> 4;
  const int ccol = lane & 15;
#pragma unroll
  for (int fn = 0; fn < 4; ++fn) {
    int col = fn * 16 + ccol;
    if (col < 60) {
      float d = db[col];
      size_t rb = (size_t)(row0 + wr + crow * 4);
#pragma unroll
      for (int r = 0; r < 4; ++r)
        deltas[(rb + r) * 60 + col] = acc[fn][r] + d;
    }
  }
}

// ---------- coords: pd = ref + deltas ; L2-normalize over the hi axis -------
__global__ void coords_kernel(const float* __restrict__ deltas,
                              float* __restrict__ vgx, float* __restrict__ vgy)
{
  int g = blockIdx.x * 256 + threadIdx.x;
  if (g >= 32 * 16 * 10 * 3) return;
  int kk = g % 3, tmp = g / 3;
  int s = tmp % 10; tmp /= 10;
  int wi = tmp % 16; int bnm = tmp / 16;
  float gxr = wi * (1.0f / 15.0f);
  float px[16], py[16];
  float sx = 0.f, sy = 0.f;
#pragma unroll
  for (int hi = 0; hi < 16; ++hi) {
    size_t base = ((size_t)((bnm * 16 + hi) * 16 + wi)) * 60 + (s * 3 + kk) * 2;
    float x = gxr + deltas[base];
    float y = hi * (1.0f / 15.0f) + deltas[base + 1];
    px[hi] = x; py[hi] = y;
    sx += x * x; sy += y * y;
  }
  float rx = 1.0f / fmaxf(sqrtf(sx), 1e-12f);
  float ry = 1.0f / fmaxf(sqrtf(sy), 1e-12f);
#pragma unroll
  for (int hi = 0; hi < 16; ++hi) {
    size_t o = ((size_t)((bnm * 16 + hi) * 16 + wi) * 10 + s) * 3 + kk;
    vgx[o] = px[hi] * rx;
    vgy[o] = py[hi] * ry;
  }
}

// ---------- MFMA attention (R9 structure) + XCD-chunked bid swizzle ---------
// R17: bid = (g&7)*1024 + (g>>3). XCD x (g%8==x) owns pids [x*1024,(x+1)*1024)
// = head m=x, 4 bnm-groups -> kp gather slice 2.6 MB, L2-resident.
__global__ __launch_bounds__(256) void attn_mfma(
    const u16* __restrict__ proj, const float* __restrict__ vgx,
    const float* __restrict__ vgy, u16* __restrict__ headf,
    float* __restrict__ attn0)
{
  const int bid = ((blockIdx.x & 7) << 10) | (blockIdx.x >> 3);
  const int m = bid >> 10, b = bid & 1023;
  const int tid = threadIdx.x;
  const int lane = tid & 63;
  const int w = tid >> 6;

  __shared__ __align__(16) u16 ksb[32][136];
  __shared__ __align__(16) u16 vt[128][32];
  __shared__ __align__(16) u16 pl[16][40];
  __shared__ float wst[30][4];
  __shared__ int   cst[30][4];

  s16x8 aq[4];
  if (w == 0) {
    size_t linb = (size_t)bid * 1280 + (size_t)(lane & 15) * 128 + (lane >> 4) * 8;
#pragma unroll
    for (int kk = 0; kk < 4; ++kk) {
      size_t lin = linb + kk * 32;
      aq[kk] = *(const s16x8*)(proj + (lin >> 10) * 5120 + (lin & 1023));
    }
  }

  if (tid < 30) {
    int t = tid, kk = t / 10, sk = t % 10;
    size_t ci = ((size_t)bid * 10 + sk) * 3 + kk;
    float gx = vgx[ci], gy = vgy[ci];
    float ix = (gx + 1.0f) * 8.0f - 0.5f;
    float iy = (gy + 1.0f) * 8.0f - 0.5f;
    float x0f = floorf(ix), y0f = floorf(iy);
    float wx1 = ix - x0f, wx0 = 1.0f - wx1;
    float wy1 = iy - y0f, wy0 = 1.0f - wy1;
    float x1f = x0f + 1.0f, y1f = y0f + 1.0f;
    bool vx0 = (x0f >= 0.f) && (x0f <= 15.f);
    bool vx1 = (x1f >= 0.f) && (x1f <= 15.f);
    bool vy0 = (y0f >= 0.f) && (y0f <= 15.f);
    bool vy1 = (y1f >= 0.f) && (y1f <= 15.f);
    int x0 = min(max((int)x0f, 0), 15);
    int x1 = min(max((int)x1f, 0), 15);
    int y0 = min(max((int)y0f, 0), 15);
    int y1 = min(max((int)y1f, 0), 15);
    wst[t][0] = wx0 * wy0 * ((vx0 && vy0) ? 1.f : 0.f);
    wst[t][1] = wx1 * wy0 * ((vx1 && vy0) ? 1.f : 0.f);
    wst[t][2] = wx0 * wy1 * ((vx0 && vy1) ? 1.f : 0.f);
    wst[t][3] = wx1 * wy1 * ((vx1 && vy1) ? 1.f : 0.f);
    cst[t][0] = x0; cst[t][1] = x1; cst[t][2] = y0; cst[t][3] = y1;
  }
  __syncthreads();

  for (int i = tid; i < 512; i += 256) {
    int t = i & 31, c = i >> 5;
    u16x8 v = (u16x8){0, 0, 0, 0, 0, 0, 0, 0};
    if (t < 30) {
      int sv = t / 3, cv = t - sv * 3;
      v = *(const u16x8*)(proj + ((size_t)(b * 10 + sv)) * 5120 + 2048 +
                          m * 384 + cv * 128 + c * 8);
    }
#pragma unroll
    for (int r = 0; r < 8; ++r)
      vt[8 * c + r][t ^ (8 * (r & 3))] = v[r];
  }

  {
    int pb = (b >> 8) << 8;
    for (int i = tid; i < 480; i += 256) {
      int t = i >> 4, c = i & 15;
      int sk = t % 10;
      int x0 = cst[t][0], x1 = cst[t][1], y0 = cst[t][2], y1 = cst[t][3];
      float w00 = wst[t][0], w10 = wst[t][1], w01 = wst[t][2], w11 = wst[t][3];
      size_t colo = 1024 + (size_t)m * 128 + c * 8;
      const u16x8 f00 = *(const u16x8*)&proj[((size_t)((pb + y0 * 16 + x0) * 10 + sk)) * 5120 + colo];
      const u16x8 f10 = *(const u16x8*)&proj[((size_t)((pb + y0 * 16 + x1) * 10 + sk)) * 5120 + colo];
      const u16x8 f01 = *(const u16x8*)&proj[((size_t)((pb + y1 * 16 + x0) * 10 + sk)) * 5120 + colo];
      const u16x8 f11 = *(const u16x8*)&proj[((size_t)((pb + y1 * 16 + x1) * 10 + sk)) * 5120 + colo];
      u16x8 o;
#pragma unroll
      for (int r = 0; r < 8; ++r) {
        float acc = w00 * bf2f(f00[r]) + w10 * bf2f(f10[r]) +
                    w01 * bf2f(f01[r]) + w11 * bf2f(f11[r]);
        o[r] = f2bf(acc);
      }
      *(u16x8*)&ksb[t][c * 8] = o;
    }
  }
  __syncthreads();

  if (w == 0) {
    f32x4 dq[2];
    dq[0] = (f32x4){0.f, 0.f, 0.f, 0.f};
    dq[1] = (f32x4){0.f, 0.f, 0.f, 0.f};
    const int lr = lane & 15, g = lane >> 4;
#pragma unroll
    for (int kk = 0; kk < 4; ++kk) {
      s16x8 b0 = *(const s16x8*)&ksb[lr][g * 8 + kk * 32];
      s16x8 b1 = *(const s16x8*)&ksb[16 + lr][g * 8 + kk * 32];
      dq[0] = __builtin_amdgcn_mfma_f32_16x16x32_bf16(aq[kk], b0, dq[0], 0, 0, 0);
      dq[1] = __builtin_amdgcn_mfma_f32_16x16x32_bf16(aq[kk], b1, dq[1], 0, 0, 0);
    }
    float p[2][4];
#pragma unroll
    for (int f = 0; f < 2; ++f) {
      int t = lr + 16 * f;
#pragma unroll
      for (int r = 0; r < 4; ++r) {
        float v = dq[f][r] * 0.08838834764831845f;
        p[f][r] = (t < 30) ? v : -1e30f;
      }
    }
#pragma unroll
    for (int r = 0; r < 4; ++r) {
      float mx = fmaxf(p[0][r], p[1][r]);
#pragma unroll
      for (int msk = 1; msk <= 8; msk <<= 1) mx = fmaxf(mx, __shfl_xor(mx, msk));
      float e0 = __expf(p[0][r] - mx);
      float e1 = __expf(p[1][r] - mx);
      float sm = e0 + e1;
#pragma unroll
      for (int msk = 1; msk <= 8; msk <<= 1) sm += __shfl_xor(sm, msk);
      float inv = 1.0f / sm;
      p[0][r] = e0 * inv;
      p[1][r] = e1 * inv;
    }
    if (g == 0) {
      attn0[(size_t)bid * 30 + lr] = p[0][0];
      if (lr < 14) attn0[(size_t)bid * 30 + 16 + lr] = p[1][0];
    }
#pragma unroll
    for (int f = 0; f < 2; ++f)
#pragma unroll
      for (int r = 0; r < 4; ++r)
        pl[g * 4 + r][lr + 16 * f] = f2bf(p[f][r]);
  }
  __syncthreads();

  const int lr = lane & 15, g = lane >> 4;
  s16x8 pa = *(const s16x8*)&pl[lr][g * 8];
#pragma unroll
  for (int qf = 0; qf < 2; ++qf) {
    int fv = w * 2 + qf;
    int v = fv * 16 + lr;
    s16x8 bv = *(const s16x8*)&vt[v][8 * (g ^ (v & 3))];
    f32x4 acc = (f32x4){0.f, 0.f, 0.f, 0.f};
    acc = __builtin_amdgcn_mfma_f32_16x16x32_bf16(pa, bv, acc, 0, 0, 0);
#pragma unroll
    for (int r = 0; r < 4; ++r) {
      int s = g * 4 + r;
      if (s < 10)
        headf[((size_t)(b * 10 + s)) * 1024 + m * 128 + v] = f2bf(acc[r]);
    }
  }
}

// ---------- attn_map[b][t] = mean_m attn0[m][b][t] --------------------------
__global__ void attnmap_kernel(const float* __restrict__ attn0, float* __restrict__ outa)
{
  int i = blockIdx.x * 256 + threadIdx.x;
  if (i >= 30720) return;
  int b = i / 30, t = i % 30;
  float s = 0.f;
  for (int mm = 0; mm < 8; ++mm) s += attn0[((size_t)mm * 1024 + b) * 30 + t];
  outa[i] = 0.125f * s;
}

// ---------------------------------------------------------------------------
extern "C" void kernel_launch(void* const* d_in, const int* in_sizes, int n_in,
                              void* d_out, int out_size, void* d_ws, size_t ws_size,
                              hipStream_t stream)
{
  const float* q  = (const float*)d_in[0];
  const float* Wq = (const float*)d_in[1];
  const float* Wk = (const float*)d_in[2];
  const float* Wv = (const float*)d_in[3];
  const float* Wo = (const float*)d_in[4];
  const float* dw = (const float*)d_in[5];
  const float* db = (const float*)d_in[6];
  float* out = (float*)d_out;
  float* attn_out = out + 10485760;

  // workspace layout (bytes): total ~165 MB. Wcat MUST follow Abf.
  char* p = (char*)d_ws;
  u16*   Abf   = (u16*)p;   p += 20971520;    // [10240][1024] bf16
  u16*   Wcat  = (u16*)p;   p += 12582912;    // [6144][1024] bf16 (B^T fused)
  u16*   proj  = (u16*)p;   p += 104857600;   // [10240][5120] bf16 (q2|kp|vp)
  u16*   headf = (u16*)p;   p += 20971520;    // [10240][1024] bf16
  u16*   dwbf  = (u16*)p;   p += 163840;      // [64][1280] bf16
  float* dels  = (float*)p; p += 1966080;     // [8192][60]
  float* vgxp  = (float*)p; p += 983040;
  float* vgyp  = (float*)p; p += 983040;
  float* attn0 = (float*)p; p += 983040;

  conv_a<<<dim3(5120), dim3(256), 0, stream>>>(q, Abf, 1310720);
  conv_w<<<dim3(3072), dim3(256), 0, stream>>>(Wq, Wk, Wv, Wo, Wcat);
  conv_dw<<<dim3(40), dim3(256), 0, stream>>>(dw, dwbf);

  // fused projections: proj = Abf @ Wcat[0:5120]^T; 512 blocks = 2 rounds
  gemm_320<<<dim3(32, 16), dim3(512), 122880, stream>>>(
      Abf, 10485760L, proj, 5120);

  delta_mfma<<<dim3(256), dim3(128), 0, stream>>>(proj, dwbf, db, dels);
  coords_kernel<<<dim3(60), dim3(256), 0, stream>>>(dels, vgxp, vgyp);
  attn_mfma<<<dim3(8192), dim3(256), 0, stream>>>(proj, vgxp, vgyp, headf, attn0);
  attnmap_kernel<<<dim3(120), dim3(256), 0, stream>>>(attn0, attn_out);

  // out = headf @ Wo^T (Wcat rows 5120..6143); 64x4 = 256 blocks = 1 round
  gemm_out<<<dim3(64, 4), dim3(512), 79872, stream>>>(
      headf, Wcat + (size_t)5120 * 1024, out, 1024);
}

// Round 18
// 206.517 us; speedup vs baseline: 5.2509x; 1.1282x over previous
//
#include <hip/hip_runtime.h>

// ---------------------------------------------------------------------------
// MultiHeadAttention_50646254354439 — R18: R17 (best, 233.0us) + LDS-tiled
// transpose for the Wcat build (conv_w was a strided gather with ~8x fetch
// amplification; now coalesced read + coalesced 128B-chunk writes).
// Dims: B=1024,S=10,D=1024,E=1024,V=KD=128,H=M=8,K=3,HI=WI=16. N=10240.
// proj=[10240][5120] bf16 = q2|kp|vp fused.
// ---------------------------------------------------------------------------

typedef float    f32x4 __attribute__((ext_vector_type(4)));
typedef short    s16x8 __attribute__((ext_vector_type(8)));
typedef unsigned short u16x8 __attribute__((ext_vector_type(8)));
typedef unsigned short u16;

__device__ __forceinline__ u16 f2bf(float f) {   // RNE float->bf16
  union { float f; unsigned u; } x; x.f = f;
  unsigned r = x.u + 0x7FFFu + ((x.u >> 16) & 1u);
  return (u16)(r >> 16);
}
__device__ __forceinline__ float bf2f(u16 u) {
  union { unsigned u; float f; } x; x.u = ((unsigned)u) << 16;
  return x.f;
}

#define ASYNC16(g, l) __builtin_amdgcn_global_load_lds(                       \
    (const __attribute__((address_space(1))) void*)(g),                       \
    (__attribute__((address_space(3))) void*)(l), 16, 0, 0)
#define WAITV(n) asm volatile("s_waitcnt vmcnt(" #n ")" ::: "memory")
#define WAITL    asm volatile("s_waitcnt lgkmcnt(0)" ::: "memory")
#define SB       __builtin_amdgcn_sched_barrier(0)
#define BAR      __builtin_amdgcn_s_barrier()

// ---------- fp32 -> bf16 elementwise ----------------------------------------
__global__ __launch_bounds__(256) void conv_a(
    const float* __restrict__ src, u16* __restrict__ dst, int n8)
{
  int i = blockIdx.x * 256 + threadIdx.x;
  if (i >= n8) return;
  const float4* s = (const float4*)src + (size_t)i * 2;
  float4 a = s[0], b = s[1];
  u16x8 o;
  o[0] = f2bf(a.x); o[1] = f2bf(a.y); o[2] = f2bf(a.z); o[3] = f2bf(a.w);
  o[4] = f2bf(b.x); o[5] = f2bf(b.y); o[6] = f2bf(b.z); o[7] = f2bf(b.w);
  *(u16x8*)(dst + (size_t)i * 8) = o;
}

// ---------- Wcat build via LDS-tiled transpose (R18) ------------------------
// Each block transposes one 64(d) x 64(k) fp32 tile of a weight segment into
// Wcat rows (bf16, K-contiguous). Coalesced float4 reads; padded [64][65]
// LDS tile (2-way conflicts = free); coalesced 128B row-chunk writes.
// c-mapping: c = cBase + kk*cStride  (Wq: cBase=h, cStride=8; others: 1).
__global__ __launch_bounds__(256) void conv_wT(
    const float* __restrict__ Wq, const float* __restrict__ Wk,
    const float* __restrict__ Wv, const float* __restrict__ Wo,
    u16* __restrict__ Wcat)
{
  __shared__ float ts[64][65];
  const int tile = blockIdx.x;     // 1536 tiles
  const int tid = threadIdx.x;

  const float* src; int K, d0, k0, cBase, cStride;
  if (tile < 256) {                       // Wq [h][1024][128]
    int h = tile >> 5, r = tile & 31;
    int dt = r >> 1, kt = r & 1;
    src = Wq + (size_t)h * 131072; K = 128;
    d0 = dt * 64; k0 = kt * 64; cBase = h; cStride = 8;
  } else if (tile < 512) {                // Wk
    int t2 = tile - 256;
    int h = t2 >> 5, r = t2 & 31;
    int dt = r >> 1, kt = r & 1;
    src = Wk + (size_t)h * 131072; K = 128;
    d0 = dt * 64; k0 = kt * 64; cBase = 1024 + h * 128; cStride = 1;
  } else if (tile < 1280) {               // Wv [h][1024][384]
    int t2 = tile - 512;
    int h = t2 / 96, r = t2 - h * 96;
    int dt = r / 6, kt = r - dt * 6;
    src = Wv + (size_t)h * 393216; K = 384;
    d0 = dt * 64; k0 = kt * 64; cBase = 2048 + h * 384; cStride = 1;
  } else {                                // Wo flat [1024][1024]
    int t2 = tile - 1280;
    int dt = t2 >> 4, kt = t2 & 15;
    src = Wo; K = 1024;
    d0 = dt * 64; k0 = kt * 64; cBase = 5120; cStride = 1;
  }

  // load 64x64 tile, coalesced float4 rows
#pragma unroll
  for (int it = 0; it < 4; ++it) {
    int row = it * 16 + (tid >> 4);
    int c4  = tid & 15;
    float4 v = *(const float4*)&src[(size_t)(d0 + row) * K + k0 + c4 * 4];
    ts[row][c4 * 4 + 0] = v.x;
    ts[row][c4 * 4 + 1] = v.y;
    ts[row][c4 * 4 + 2] = v.z;
    ts[row][c4 * 4 + 3] = v.w;
  }
  __syncthreads();

  // write transposed: 64 output rows (kk), each 64 bf16 = 8 u16x8 chunks
#pragma unroll
  for (int it = 0; it < 2; ++it) {
    int idx = it * 256 + tid;
    int r  = idx >> 3;          // kk offset 0..63
    int s8 = idx & 7;           // d-chunk 0..7
    u16x8 o;
#pragma unroll
    for (int j = 0; j < 8; ++j) o[j] = f2bf(ts[s8 * 8 + j][r]);
    int c = cBase + (k0 + r) * cStride;
    *(u16x8*)&Wcat[(size_t)c * 1024 + d0 + s8 * 8] = o;
  }
}

// ---------- dw -> bf16 [64][1280] (rows >=60 dummy=row0, never written) -----
__global__ __launch_bounds__(256) void conv_dw(
    const float* __restrict__ dw, u16* __restrict__ dwbf)
{
  int i = blockIdx.x * 256 + threadIdx.x;   // 64*160 = 10240 chunks
  if (i >= 10240) return;
  int row = i / 160, ch = i - row * 160;
  int srow = (row < 60) ? row : 0;
  const float4* s = (const float4*)(dw + (size_t)srow * 1280 + ch * 8);
  float4 a = s[0], b = s[1];
  u16x8 o;
  o[0] = f2bf(a.x); o[1] = f2bf(a.y); o[2] = f2bf(a.z); o[3] = f2bf(a.w);
  o[4] = f2bf(b.x); o[5] = f2bf(b.y); o[6] = f2bf(b.z); o[7] = f2bf(b.w);
  *(u16x8*)(dwbf + (size_t)row * 1280 + ch * 8) = o;
}

// ---------- 320x320 bf16 MFMA GEMM (proj): C = A @ Bt^T ---------------------
// R9/R14-proven: 512 blocks = 2 exact rounds, triple-buffered 40KB units,
// counted vmcnt(5), one barrier/tile. DO NOT add register state (R11/R15).
__global__ __launch_bounds__(512, 2) void gemm_320(
    const u16* __restrict__ base, long bOff, u16* __restrict__ C, int ldc)
{
  extern __shared__ __align__(16) char smem[];   // 3 x 40960 = 122880 B
  const int tid = threadIdx.x;
  const int l   = tid & 63;
  const int wid = tid >> 6;
  const int wm  = wid >> 2;
  const int wn  = wid & 3;
  const int row0 = blockIdx.x * 320;
  const int col0 = blockIdx.y * 320;

  int eoff[5];
#pragma unroll
  for (int j = 0; j < 5; ++j) {
    int c = j * 512 + tid;
    int mc = (c < 1280) ? c : c - 1280;
    int rp = mc >> 3, s = mc & 7, gs = s ^ (rp & 7);
    int grow = rp * 2 + (gs >> 2), gk = (gs & 3) * 8;
    eoff[j] = (c < 1280) ? ((row0 + grow) * 1024 + gk)
                         : (int)(bOff + (size_t)(col0 + grow) * 1024 + gk);
  }

#define STG320(tt, bb) do {                                                   \
    _Pragma("unroll")                                                         \
    for (int j_ = 0; j_ < 5; ++j_)                                            \
      ASYNC16(base + eoff[j_] + (tt) * 32,                                    \
              smem + (bb) * 40960 + (j_ * 512 + tid) * 16);                   \
  } while (0)

  const int lrow = l & 15, lk = l >> 4;
  int aoff[10], boff[5];
  {
    int rowA = wm * 160 + lrow;
    int rpA = rowA >> 1, odA = (rowA & 1) << 2;
#pragma unroll
    for (int fm = 0; fm < 10; ++fm) {
      int rp = rpA + fm * 8;
      aoff[fm] = rp * 128 + (((odA | lk) ^ (rp & 7)) * 16);
    }
    int rowB = wn * 80 + lrow;
    int rpB = rowB >> 1, odB = (rowB & 1) << 2;
#pragma unroll
    for (int fn = 0; fn < 5; ++fn) {
      int rp = rpB + fn * 8;
      boff[fn] = 20480 + rp * 128 + (((odB | lk) ^ (rp & 7)) * 16);
    }
  }

  f32x4 acc[10][5];
#pragma unroll
  for (int i = 0; i < 10; ++i)
#pragma unroll
    for (int j = 0; j < 5; ++j) acc[i][j] = (f32x4){0.f, 0.f, 0.f, 0.f};

  STG320(0, 0); STG320(1, 1);
  WAITV(5);
  SB; BAR; SB;

  for (int t = 0; t < 32; ++t) {
    const int cb = t % 3;
    if (t + 2 < 32) STG320(t + 2, (t + 2) % 3);
    const char* Ab = smem + cb * 40960;
    s16x8 bR[5];
#pragma unroll
    for (int fn = 0; fn < 5; ++fn) bR[fn] = *(const s16x8*)(Ab + boff[fn]);
#pragma unroll
    for (int fm = 0; fm < 10; ++fm) {
      s16x8 aT = *(const s16x8*)(Ab + aoff[fm]);
#pragma unroll
      for (int fn = 0; fn < 5; ++fn)
        acc[fm][fn] = __builtin_amdgcn_mfma_f32_16x16x32_bf16(
            aT, bR[fn], acc[fm][fn], 0, 0, 0);
    }
    if (t + 2 < 32) { WAITV(5); }
    else if (t == 30) { WAITV(0); }
    SB; BAR; SB;
  }
#undef STG320

  const int crow = l >> 4, ccol = l & 15;
#pragma unroll
  for (int fm = 0; fm < 10; ++fm)
#pragma unroll
    for (int fn = 0; fn < 5; ++fn) {
      size_t rb = (size_t)(row0 + wm * 160 + fm * 16 + crow * 4);
      int col = col0 + wn * 80 + fn * 16 + ccol;
#pragma unroll
      for (int r = 0; r < 4; ++r)
        C[(rb + r) * ldc + col] = f2bf(acc[fm][fn][r]);
    }
}

// ---------- out GEMM: 160x256 tile, 256 blocks = 1 full-resident round ------
// R14-proven. C fp32 = A @ Bt^T. 8 waves (2M x 4N), wave tile 80x64.
__global__ __launch_bounds__(512, 2) void gemm_out(
    const u16* __restrict__ A, const u16* __restrict__ Bt,
    float* __restrict__ C, int ldc)
{
  extern __shared__ __align__(16) char smem[];   // 3 x 26624 = 79872 B
  const int tid = threadIdx.x;
  const int l   = tid & 63;
  const int wid = tid >> 6;
  const int wm  = wid >> 2;
  const int wn  = wid & 3;
  const int row0 = blockIdx.x * 160;
  const int col0 = blockIdx.y * 256;

  const u16* gsrc[4];
  bool gact[4];
#pragma unroll
  for (int j = 0; j < 4; ++j) {
    int c = j * 512 + tid;
    gact[j] = (c < 1664);
    int cc = gact[j] ? c : 0;
    int mc = (cc < 640) ? cc : cc - 640;
    int rp = mc >> 3, s = mc & 7, gs = s ^ (rp & 7);
    int grow = rp * 2 + (gs >> 2), gk = (gs & 3) * 8;
    gsrc[j] = (cc < 640) ? (A + (size_t)(row0 + grow) * 1024 + gk)
                         : (Bt + (size_t)(col0 + grow) * 1024 + gk);
  }

#define STGO(tt, bb) do {                                                     \
    _Pragma("unroll")                                                         \
    for (int j_ = 0; j_ < 4; ++j_)                                            \
      if (gact[j_])                                                           \
        ASYNC16(gsrc[j_] + (tt) * 32,                                         \
                smem + (bb) * 26624 + (j_ * 512 + tid) * 16);                 \
  } while (0)

  const int lrow = l & 15, lk = l >> 4;
  int aoff[5], boff[4];
  {
    int rowA = wm * 80 + lrow;
    int rpA = rowA >> 1, odA = (rowA & 1) << 2;
#pragma unroll
    for (int fm = 0; fm < 5; ++fm) {
      int rp = rpA + fm * 8;
      aoff[fm] = rp * 128 + (((odA | lk) ^ (rp & 7)) * 16);
    }
    int rowB = wn * 64 + lrow;
    int rpB = rowB >> 1, odB = (rowB & 1) << 2;
#pragma unroll
    for (int fn = 0; fn < 4; ++fn) {
      int rp = rpB + fn * 8;
      boff[fn] = 10240 + rp * 128 + (((odB | lk) ^ (rp & 7)) * 16);
    }
  }

  f32x4 acc[5][4];
#pragma unroll
  for (int i = 0; i < 5; ++i)
#pragma unroll
    for (int j = 0; j < 4; ++j) acc[i][j] = (f32x4){0.f, 0.f, 0.f, 0.f};

  STGO(0, 0); STGO(1, 1);
  WAITV(3);
  SB; BAR; SB;

  for (int t = 0; t < 32; ++t) {
    const int cb = t % 3;
    if (t + 2 < 32) STGO(t + 2, (t + 2) % 3);
    const char* Ab = smem + cb * 26624;
    s16x8 bR[4];
#pragma unroll
    for (int fn = 0; fn < 4; ++fn) bR[fn] = *(const s16x8*)(Ab + boff[fn]);
#pragma unroll
    for (int fm = 0; fm < 5; ++fm) {
      s16x8 aT = *(const s16x8*)(Ab + aoff[fm]);
#pragma unroll
      for (int fn = 0; fn < 4; ++fn)
        acc[fm][fn] = __builtin_amdgcn_mfma_f32_16x16x32_bf16(
            aT, bR[fn], acc[fm][fn], 0, 0, 0);
    }
    if (t + 2 < 32) { WAITV(3); }
    else if (t == 30) { WAITV(0); }
    SB; BAR; SB;
  }
#undef STGO

  const int crow = l >> 4, ccol = l & 15;
#pragma unroll
  for (int fm = 0; fm < 5; ++fm)
#pragma unroll
    for (int fn = 0; fn < 4; ++fn) {
      size_t rb = (size_t)(row0 + wm * 80 + fm * 16 + crow * 4);
      int col = col0 + wn * 64 + fn * 16 + ccol;
#pragma unroll
      for (int r = 0; r < 4; ++r)
        C[(rb + r) * ldc + col] = acc[fm][fn][r];
    }
}

// ---------- deltas = q2view[8192][1280] @ dwbf^T + db -----------------------
// R16-proven: 256 blocks (full chip) x 128 threads, 32-row tiles, WAITV(6).
__global__ __launch_bounds__(128) void delta_mfma(
    const u16* __restrict__ proj, const u16* __restrict__ dwbf,
    const float* __restrict__ db, float* __restrict__ deltas)
{
  __shared__ __align__(16) u16 As[4][32 * 32];
  __shared__ __align__(16) u16 Bs[4][64 * 32];
  const int tid  = threadIdx.x;
  const int lane = tid & 63;
  const int w    = tid >> 6;
  const int row0 = blockIdx.x * 32;
  const int wr   = w * 16;
  const int lrow = lane & 15;
  const int lk   = lane >> 4;

  f32x4 acc[4];
#pragma unroll
  for (int j = 0; j < 4; ++j) acc[j] = (f32x4){0.f, 0.f, 0.f, 0.f};

  const size_t lin0 = (size_t)(row0 + (tid >> 2)) * 1280 + (tid & 3) * 8;
  const u16* Bg0 = dwbf + (size_t)(tid >> 2) * 1280 + (tid & 3) * 8;
  const u16* Bg1 = dwbf + (size_t)((128 + tid) >> 2) * 1280 + (tid & 3) * 8;

#define STD(kk, bb) do {                                                      \
    size_t lin_ = lin0 + (kk) * 32;                                           \
    ASYNC16(proj + (lin_ >> 10) * 5120 + (lin_ & 1023),                       \
            (char*)As + (bb) * 2048 + tid * 16);                              \
    ASYNC16(Bg0 + (kk) * 32, (char*)Bs + (bb) * 4096 + tid * 16);             \
    ASYNC16(Bg1 + (kk) * 32, (char*)Bs + (bb) * 4096 + (128 + tid) * 16);     \
  } while (0)

  const int aoff = (wr + lrow) * 64 + lk * 16;
  int boff[4];
#pragma unroll
  for (int f = 0; f < 4; ++f) boff[f] = (f * 16 + lrow) * 64 + lk * 16;

  STD(0, 0); STD(1, 1); STD(2, 2);
  WAITV(6);
  SB; BAR; SB;

  for (int k = 0; k < 40; ++k) {
    const int bb = k & 3;
    if (k + 3 < 40) STD(k + 3, (k + 3) & 3);
    s16x8 af = *(const s16x8*)((const char*)As + bb * 2048 + aoff);
#pragma unroll
    for (int fn = 0; fn < 4; ++fn) {
      s16x8 bfr = *(const s16x8*)((const char*)Bs + bb * 4096 + boff[fn]);
      acc[fn] = __builtin_amdgcn_mfma_f32_16x16x32_bf16(af, bfr, acc[fn], 0, 0, 0);
    }
    if (k < 37)      { WAITV(6); }
    else if (k == 37){ WAITV(3); }
    else if (k == 38){ WAITV(0); }
    SB; BAR; SB;
  }
#undef STD

  const int crow = lane >> 4;
  const int ccol = lane & 15;
#pragma unroll
  for (int fn = 0; fn < 4; ++fn) {
    int col = fn * 16 + ccol;
    if (col < 60) {
      float d = db[col];
      size_t rb = (size_t)(row0 + wr + crow * 4);
#pragma unroll
      for (int r = 0; r < 4; ++r)
        deltas[(rb + r) * 60 + col] = acc[fn][r] + d;
    }
  }
}

// ---------- coords: pd = ref + deltas ; L2-normalize over the hi axis -------
__global__ void coords_kernel(const float* __restrict__ deltas,
                              float* __restrict__ vgx, float* __restrict__ vgy)
{
  int g = blockIdx.x * 256 + threadIdx.x;
  if (g >= 32 * 16 * 10 * 3) return;
  int kk = g % 3, tmp = g / 3;
  int s = tmp % 10; tmp /= 10;
  int wi = tmp % 16; int bnm = tmp / 16;
  float gxr = wi * (1.0f / 15.0f);
  float px[16], py[16];
  float sx = 0.f, sy = 0.f;
#pragma unroll
  for (int hi = 0; hi < 16; ++hi) {
    size_t base = ((size_t)((bnm * 16 + hi) * 16 + wi)) * 60 + (s * 3 + kk) * 2;
    float x = gxr + deltas[base];
    float y = hi * (1.0f / 15.0f) + deltas[base + 1];
    px[hi] = x; py[hi] = y;
    sx += x * x; sy += y * y;
  }
  float rx = 1.0f / fmaxf(sqrtf(sx), 1e-12f);
  float ry = 1.0f / fmaxf(sqrtf(sy), 1e-12f);
#pragma unroll
  for (int hi = 0; hi < 16; ++hi) {
    size_t o = ((size_t)((bnm * 16 + hi) * 16 + wi) * 10 + s) * 3 + kk;
    vgx[o] = px[hi] * rx;
    vgy[o] = py[hi] * ry;
  }
}

// ---------- MFMA attention (R9 structure) + XCD-chunked bid swizzle ---------
__global__ __launch_bounds__(256) void attn_mfma(
    const u16* __restrict__ proj, const float* __restrict__ vgx,
    const float* __restrict__ vgy, u16* __restrict__ headf,
    float* __restrict__ attn0)
{
  const int bid = ((blockIdx.x & 7) << 10) | (blockIdx.x >> 3);
  const int m = bid >> 10, b = bid & 1023;
  const int tid = threadIdx.x;
  const int lane = tid & 63;
  const int w = tid >> 6;

  __shared__ __align__(16) u16 ksb[32][136];
  __shared__ __align__(16) u16 vt[128][32];
  __shared__ __align__(16) u16 pl[16][40];
  __shared__ float wst[30][4];
  __shared__ int   cst[30][4];

  s16x8 aq[4];
  if (w == 0) {
    size_t linb = (size_t)bid * 1280 + (size_t)(lane & 15) * 128 + (lane >> 4) * 8;
#pragma unroll
    for (int kk = 0; kk < 4; ++kk) {
      size_t lin = linb + kk * 32;
      aq[kk] = *(const s16x8*)(proj + (lin >> 10) * 5120 + (lin & 1023));
    }
  }

  if (tid < 30) {
    int t = tid, kk = t / 10, sk = t % 10;
    size_t ci = ((size_t)bid * 10 + sk) * 3 + kk;
    float gx = vgx[ci], gy = vgy[ci];
    float ix = (gx + 1.0f) * 8.0f - 0.5f;
    float iy = (gy + 1.0f) * 8.0f - 0.5f;
    float x0f = floorf(ix), y0f = floorf(iy);
    float wx1 = ix - x0f, wx0 = 1.0f - wx1;
    float wy1 = iy - y0f, wy0 = 1.0f - wy1;
    float x1f = x0f + 1.0f, y1f = y0f + 1.0f;
    bool vx0 = (x0f >= 0.f) && (x0f <= 15.f);
    bool vx1 = (x1f >= 0.f) && (x1f <= 15.f);
    bool vy0 = (y0f >= 0.f) && (y0f <= 15.f);
    bool vy1 = (y1f >= 0.f) && (y1f <= 15.f);
    int x0 = min(max((int)x0f, 0), 15);
    int x1 = min(max((int)x1f, 0), 15);
    int y0 = min(max((int)y0f, 0), 15);
    int y1 = min(max((int)y1f, 0), 15);
    wst[t][0] = wx0 * wy0 * ((vx0 && vy0) ? 1.f : 0.f);
    wst[t][1] = wx1 * wy0 * ((vx1 && vy0) ? 1.f : 0.f);
    wst[t][2] = wx0 * wy1 * ((vx0 && vy1) ? 1.f : 0.f);
    wst[t][3] = wx1 * wy1 * ((vx1 && vy1) ? 1.f : 0.f);
    cst[t][0] = x0; cst[t][1] = x1; cst[t][2] = y0; cst[t][3] = y1;
  }
  __syncthreads();

  for (int i = tid; i < 512; i += 256) {
    int t = i & 31, c = i >> 5;
    u16x8 v = (u16x8){0, 0, 0, 0, 0, 0, 0, 0};
    if (t < 30) {
      int sv = t / 3, cv = t - sv * 3;
      v = *(const u16x8*)(proj + ((size_t)(b * 10 + sv)) * 5120 + 2048 +
                          m * 384 + cv * 128 + c * 8);
    }
#pragma unroll
    for (int r = 0; r < 8; ++r)
      vt[8 * c + r][t ^ (8 * (r & 3))] = v[r];
  }

  {
    int pb = (b >> 8) << 8;
    for (int i = tid; i < 480; i += 256) {
      int t = i >> 4, c = i & 15;
      int sk = t % 10;
      int x0 = cst[t][0], x1 = cst[t][1], y0 = cst[t][2], y1 = cst[t][3];
      float w00 = wst[t][0], w10 = wst[t][1], w01 = wst[t][2], w11 = wst[t][3];
      size_t colo = 1024 + (size_t)m * 128 + c * 8;
      const u16x8 f00 = *(const u16x8*)&proj[((size_t)((pb + y0 * 16 + x0) * 10 + sk)) * 5120 + colo];
      const u16x8 f10 = *(const u16x8*)&proj[((size_t)((pb + y0 * 16 + x1) * 10 + sk)) * 5120 + colo];
      const u16x8 f01 = *(const u16x8*)&proj[((size_t)((pb + y1 * 16 + x0) * 10 + sk)) * 5120 + colo];
      const u16x8 f11 = *(const u16x8*)&proj[((size_t)((pb + y1 * 16 + x1) * 10 + sk)) * 5120 + colo];
      u16x8 o;
#pragma unroll
      for (int r = 0; r < 8; ++r) {
        float acc = w00 * bf2f(f00[r]) + w10 * bf2f(f10[r]) +
                    w01 * bf2f(f01[r]) + w11 * bf2f(f11[r]);
        o[r] = f2bf(acc);
      }
      *(u16x8*)&ksb[t][c * 8] = o;
    }
  }
  __syncthreads();

  if (w == 0) {
    f32x4 dq[2];
    dq[0] = (f32x4){0.f, 0.f, 0.f, 0.f};
    dq[1] = (f32x4){0.f, 0.f, 0.f, 0.f};
    const int lr = lane & 15, g = lane >> 4;
#pragma unroll
    for (int kk = 0; kk < 4; ++kk) {
      s16x8 b0 = *(const s16x8*)&ksb[lr][g * 8 + kk * 32];
      s16x8 b1 = *(const s16x8*)&ksb[16 + lr][g * 8 + kk * 32];
      dq[0] = __builtin_amdgcn_mfma_f32_16x16x32_bf16(aq[kk], b0, dq[0], 0, 0, 0);
      dq[1] = __builtin_amdgcn_mfma_f32_16x16x32_bf16(aq[kk], b1, dq[1], 0, 0, 0);
    }
    float p[2][4];
#pragma unroll
    for (int f = 0; f < 2; ++f) {
      int t = lr + 16 * f;
#pragma unroll
      for (int r = 0; r < 4; ++r) {
        float v = dq[f][r] * 0.08838834764831845f;
        p[f][r] = (t < 30) ? v : -1e30f;
      }
    }
#pragma unroll
    for (int r = 0; r < 4; ++r) {
      float mx = fmaxf(p[0][r], p[1][r]);
#pragma unroll
      for (int msk = 1; msk <= 8; msk <<= 1) mx = fmaxf(mx, __shfl_xor(mx, msk));
      float e0 = __expf(p[0][r] - mx);
      float e1 = __expf(p[1][r] - mx);
      float sm = e0 + e1;
#pragma unroll
      for (int msk = 1; msk <= 8; msk <<= 1) sm += __shfl_xor(sm, msk);
      float inv = 1.0f / sm;
      p[0][r] = e0 * inv;
      p[1][r] = e1 * inv;
    }
    if (g == 0) {
      attn0[(size_t)bid * 30 + lr] = p[0][0];
      if (lr < 14) attn0[(size_t)bid * 30 + 16 + lr] = p[1][0];
    }
#pragma unroll
    for (int f = 0; f < 2; ++f)
#pragma unroll
      for (int r = 0; r < 4; ++r)
        pl[g * 4 + r][lr + 16 * f] = f2bf(p[f][r]);
  }
  __syncthreads();

  const int lr = lane & 15, g = lane >> 4;
  s16x8 pa = *(const s16x8*)&pl[lr][g * 8];
#pragma unroll
  for (int qf = 0; qf < 2; ++qf) {
    int fv = w * 2 + qf;
    int v = fv * 16 + lr;
    s16x8 bv = *(const s16x8*)&vt[v][8 * (g ^ (v & 3))];
    f32x4 acc = (f32x4){0.f, 0.f, 0.f, 0.f};
    acc = __builtin_amdgcn_mfma_f32_16x16x32_bf16(pa, bv, acc, 0, 0, 0);
#pragma unroll
    for (int r = 0; r < 4; ++r) {
      int s = g * 4 + r;
      if (s < 10)
        headf[((size_t)(b * 10 + s)) * 1024 + m * 128 + v] = f2bf(acc[r]);
    }
  }
}

// ---------- attn_map[b][t] = mean_m attn0[m][b][t] --------------------------
__global__ void attnmap_kernel(const float* __restrict__ attn0, float* __restrict__ outa)
{
  int i = blockIdx.x * 256 + threadIdx.x;
  if (i >= 30720) return;
  int b = i / 30, t = i % 30;
  float s = 0.f;
  for (int mm = 0; mm < 8; ++mm) s += attn0[((size_t)mm * 1024 + b) * 30 + t];
  outa[i] = 0.125f * s;
}

// ---------------------------------------------------------------------------
extern "C" void kernel_launch(void* const* d_in, const int* in_sizes, int n_in,
                              void* d_out, int out_size, void* d_ws, size_t ws_size,
                              hipStream_t stream)
{
  const float* q  = (const float*)d_in[0];
  const float* Wq = (const float*)d_in[1];
  const float* Wk = (const float*)d_in[2];
  const float* Wv = (const float*)d_in[3];
  const float* Wo = (const float*)d_in[4];
  const float* dw = (const float*)d_in[5];
  const float* db = (const float*)d_in[6];
  float* out = (float*)d_out;
  float* attn_out = out + 10485760;

  // workspace layout (bytes): total ~165 MB. Wcat MUST follow Abf.
  char* p = (char*)d_ws;
  u16*   Abf   = (u16*)p;   p += 20971520;    // [10240][1024] bf16
  u16*   Wcat  = (u16*)p;   p += 12582912;    // [6144][1024] bf16 (B^T fused)
  u16*   proj  = (u16*)p;   p += 104857600;   // [10240][5120] bf16 (q2|kp|vp)
  u16*   headf = (u16*)p;   p += 20971520;    // [10240][1024] bf16
  u16*   dwbf  = (u16*)p;   p += 163840;      // [64][1280] bf16
  float* dels  = (float*)p; p += 1966080;     // [8192][60]
  float* vgxp  = (float*)p; p += 983040;
  float* vgyp  = (float*)p; p += 983040;
  float* attn0 = (float*)p; p += 983040;

  conv_a<<<dim3(5120), dim3(256), 0, stream>>>(q, Abf, 1310720);
  conv_wT<<<dim3(1536), dim3(256), 0, stream>>>(Wq, Wk, Wv, Wo, Wcat);
  conv_dw<<<dim3(40), dim3(256), 0, stream>>>(dw, dwbf);

  // fused projections: proj = Abf @ Wcat[0:5120]^T; 512 blocks = 2 rounds
  gemm_320<<<dim3(32, 16), dim3(512), 122880, stream>>>(
      Abf, 10485760L, proj, 5120);

  delta_mfma<<<dim3(256), dim3(128), 0, stream>>>(proj, dwbf, db, dels);
  coords_kernel<<<dim3(60), dim3(256), 0, stream>>>(dels, vgxp, vgyp);
  attn_mfma<<<dim3(8192), dim3(256), 0, stream>>>(proj, vgxp, vgyp, headf, attn0);
  attnmap_kernel<<<dim3(120), dim3(256), 0, stream>>>(attn0, attn_out);

  // out = headf @ Wo^T (Wcat rows 5120..6143); 64x4 = 256 blocks = 1 round
  gemm_out<<<dim3(64, 4), dim3(512), 79872, stream>>>(
      headf, Wcat + (size_t)5120 * 1024, out, 1024);
}